// Round 1
// 968.661 us; speedup vs baseline: 1.0483x; 1.0483x over previous
//
#include <hip/hip_runtime.h>
#include <math.h>

#define EMBED 2048
#define DFF   8192
#define TOK   4096
#define SEQ   2048
#define HEADS 16
#define HD    128
#define LDQ   6144   // qkv row stride in elements (q|k|v concatenated)

typedef __attribute__((ext_vector_type(8))) short short8;
typedef __attribute__((ext_vector_type(4))) float f32x4;

__device__ __forceinline__ unsigned short f2bf(float f) {
    unsigned int u = __float_as_uint(f);
    return (unsigned short)((u + 0x7FFFu + ((u >> 16) & 1u)) >> 16);  // RNE
}
__device__ __forceinline__ float bf2f(unsigned short s) {
    return __uint_as_float(((unsigned int)s) << 16);
}

// async global->LDS, 16B per lane. LDS dest = wave-uniform base + lane*16.
__device__ __forceinline__ void async16(const void* g, void* l) {
    __builtin_amdgcn_global_load_lds((const __attribute__((address_space(1))) void*)g,
                                     (__attribute__((address_space(3))) void*)l, 16, 0, 0);
}

// fast GELU (tanh form): v * sigmoid(1.5957691*(v + 0.044715 v^3)); |err|<~1e-3
__device__ __forceinline__ float gelu_fast(float v) {
    const float y = 1.5957691216057308f * (v + 0.044715f * v * v * v);
    return v / (1.0f + __expf(-y));
}

// ---------------------------------------------------------------------------
// bf16 MFMA GEMM: C[M,N](bf16) = A[M,K](bf16) @ Wt[N,K](bf16)^T + bias (+epi)
// 128x128 tile, BK=32, 256 thr = 4 waves (2x2 of 64x64), 16x16x32 MFMA.
// Single-barrier double-buffered K-loop (R4 win: loads for tile k+1 in
// flight across tile k's compute). 2D grid, N-fastest (R3 mapping — the R4
// XCD swizzle raised FETCH 107->168 MB; reverted).
// Epilogue: acc -> LDS (f32, 2 passes) -> 16B coalesced bf16 stores; fixes
// the R4 2x write amplification (scattered 2B stores -> 32B < 64B sector).
// MODE: 0 plain, 1 +resid f32, 2 +GELU, 3 +resid bf16. Output always bf16.
// ---------------------------------------------------------------------------
template<int MODE>
__global__ __launch_bounds__(256, 2)
void gemm_bf16(const unsigned short* __restrict__ A, const unsigned short* __restrict__ B,
               const float* __restrict__ bias, const void* __restrict__ resid,
               unsigned short* __restrict__ C, int M, int N, int K, int lda)
{
    __shared__ __align__(16) float smemf[8448];          // 33.8 KB, multi-use
    unsigned short* As = (unsigned short*)smemf;         // As[2][4096] u16
    unsigned short* Bs = As + 8192;                      // Bs[2][4096] u16
    float* Cs = smemf;                                   // Cs[64][132] f32 (epilogue)

    const int t = threadIdx.x;
    const int w = t >> 6, l = t & 63;
    const int quad = l >> 4, m16 = l & 15;
    const long bm = (long)blockIdx.y * 128, bn = (long)blockIdx.x * 128;
    const int wr = (w >> 1)*64, wc = (w & 1)*64;   // this wave's 64x64 quadrant

    f32x4 acc[4][4] = {};

    const int srow = w*16 + (l >> 2);   // staging row (+u*64)
    const int sslot = l & 3;
    const unsigned short* Ag = A + (size_t)bm*lda;
    const unsigned short* Bg = B + (size_t)bn*K;

    // prologue: stage tile 0 -> buffer 0
#pragma unroll
    for (int u = 0; u < 2; ++u) {
        const int row = u*64 + srow;
        const int c = sslot ^ ((row >> 1) & 3);
        async16(Ag + (size_t)row*lda + c*8, &As[u*2048 + w*512]);
        async16(Bg + (size_t)row*K   + c*8, &Bs[u*2048 + w*512]);
    }

    const int iters = K >> 5;
    for (int it = 0; it < iters; ++it) {
        __syncthreads();   // drains tile-it glds (in flight since last iter)
        if (it + 1 < iters) {
            const int k0 = (it + 1) << 5;
            const int bo = ((it + 1) & 1) * 4096;
#pragma unroll
            for (int u = 0; u < 2; ++u) {
                const int row = u*64 + srow;
                const int c = sslot ^ ((row >> 1) & 3);
                async16(Ag + (size_t)row*lda + k0 + c*8, &As[bo + u*2048 + w*512]);
                async16(Bg + (size_t)row*K   + k0 + c*8, &Bs[bo + u*2048 + w*512]);
            }
        }
        const int co = (it & 1) * 4096;
        short8 af[4], bf[4];
#pragma unroll
        for (int s = 0; s < 4; ++s) {
            const int ra = wr + s*16 + m16;
            const int sla = quad ^ ((ra >> 1) & 3);
            af[s] = *(const short8*)&As[co + ra*32 + sla*8];
            const int rb = wc + s*16 + m16;
            const int slb = quad ^ ((rb >> 1) & 3);
            bf[s] = *(const short8*)&Bs[co + rb*32 + slb*8];
        }
#pragma unroll
        for (int ms = 0; ms < 4; ++ms)
#pragma unroll
            for (int ns = 0; ns < 4; ++ns)
                acc[ms][ns] = __builtin_amdgcn_mfma_f32_16x16x32_bf16(af[ms], bf[ns], acc[ms][ns], 0, 0, 0);
    }

    // ---- epilogue via LDS: 2 passes of 64 rows ----
    const int ecol = (t & 15) * 8;          // this lane's 8 output cols
    float bias8[8];
#pragma unroll
    for (int i = 0; i < 8; ++i) bias8[i] = bias[bn + ecol + i];

#pragma unroll
    for (int pass = 0; pass < 2; ++pass) {
        __syncthreads();   // prior LDS use (K-loop buffers / previous pass) done
        if ((w >> 1) == pass) {   // waves owning rows [pass*64, pass*64+64) stage
#pragma unroll
            for (int ms = 0; ms < 4; ++ms)
#pragma unroll
                for (int ns = 0; ns < 4; ++ns)
#pragma unroll
                    for (int r = 0; r < 4; ++r)
                        Cs[(ms*16 + quad*4 + r)*132 + wc + ns*16 + m16] = acc[ms][ns][r];
        }
        __syncthreads();
#pragma unroll
        for (int j = 0; j < 4; ++j) {
            const int row = j*16 + (t >> 4);
            float v[8];
            *(f32x4*)&v[0] = *(const f32x4*)&Cs[row*132 + ecol];
            *(f32x4*)&v[4] = *(const f32x4*)&Cs[row*132 + ecol + 4];
            const long gr = bm + pass*64 + row;
            const long go = gr*N + bn + ecol;
            float r8[8];
            if (MODE == 1) {
                *(f32x4*)&r8[0] = *(const f32x4*)((const float*)resid + go);
                *(f32x4*)&r8[4] = *(const f32x4*)((const float*)resid + go + 4);
            }
            short8 rb16;
            if (MODE == 3) rb16 = *(const short8*)((const unsigned short*)resid + go);
            short8 o;
#pragma unroll
            for (int i = 0; i < 8; ++i) {
                float y = v[i] + bias8[i];
                if (MODE == 1) y += r8[i];
                if (MODE == 3) y += bf2f((unsigned short)rb16[i]);
                if (MODE == 2) y = gelu_fast(y);
                o[i] = (short)f2bf(y);
            }
            *(short8*)&C[go] = o;
        }
    }
}

// ---------------------------------------------------------------------------
// Flash attention, bf16 MFMA. One block = (b, h, 64-row Q tile). 256 thr.
// qkv layout: [4096 rows][6144] bf16 = q|k|v, head h at cols h*128 (+0/2048/4096).
// O is written in-place over the Q columns (only this block reads them).
//
// R5 restructure (latency-bound per rocprof: MfmaUtil 12.7%, HBM 8.8%, ~60%
// stall): K is double-buffered with async16 prefetch issued at the TOP of
// iteration kt for tile kt+1 (single-barrier GEMM-style pipeline); V uses the
// T14 async-split — global loads -> regs at the top (in flight across all of
// compute), pack + ds_write only after the post-PV barrier. Q's staging
// buffer overlays K-buffer-1 (Q dead after frag load), so LDS stays at
// 60,416 B = 2 blocks/CU. O-rescale skipped when the running max didn't grow
// (al==1.0 exactly -> bit-identical).
// ---------------------------------------------------------------------------
__global__ __launch_bounds__(256, 2)
void attn_flash(unsigned short* __restrict__ qkv)
{
    __shared__ unsigned short Ks2[2][64*128]; // K dbuf; buf1 doubles as Q staging
    __shared__ unsigned short Vt[128*72];     // V^T [d][j], col j ^ (((d>>5)&3)<<3)
    __shared__ unsigned short Ps[4*16*72];    // per-wave P scratch

    const int t = threadIdx.x;
    const int w = t >> 6, l = t & 63;
    const int quad = l >> 4, m16 = l & 15;

    const int qt = blockIdx.x & 31;
    const int bh = blockIdx.x >> 5;
    const int b = bh >> 4, h = bh & 15;

    const long rowq = (long)b*SEQ + qt*64;
    const long rowb = (long)b*SEQ;
    const int qc = h*HD;
    const int kc = EMBED + h*HD;
    const int vc = 2*EMBED + h*HD;

    const int rbase = w*4 + (l >> 4);   // K/Q staging row base
    const int slot  = l & 15;           // K/Q staging 16B slot
    const int vslot = t & 15;           // V staging d-slot
    const int vrp   = t >> 4;           // V staging row-pair base

    unsigned short* Qs = Ks2[1];

    // ---- prologue: V0 -> regs (issued first = oldest vmcnt entries),
    //      Q -> Qs(=Ks2[1]) and K0 -> Ks2[0] async ----
    short8 va[2], vb[2];
#pragma unroll
    for (int u = 0; u < 2; ++u) {
        const int rp = u*16 + vrp;
        va[u] = *(const short8*)(qkv + (rowb + 2*rp    )*LDQ + vc + vslot*8);
        vb[u] = *(const short8*)(qkv + (rowb + 2*rp + 1)*LDQ + vc + vslot*8);
    }
#pragma unroll
    for (int u = 0; u < 4; ++u) {
        const int row = u*16 + rbase;
        const int c = slot ^ ((row >> 1) & 7);
        async16(qkv + (rowq + row)*LDQ + qc + c*8, Qs + u*2048 + w*512);
        async16(qkv + (rowb + row)*LDQ + kc + c*8, &Ks2[0][u*2048 + w*512]);
    }
    // write V0 (waits vmcnt only down to the va/vb loads; Q/K glds stay in flight)
#pragma unroll
    for (int u = 0; u < 2; ++u) {
        const int rp = u*16 + vrp;
#pragma unroll
        for (int i = 0; i < 8; ++i) {
            const int d = vslot*8 + i;
            const int col = (2*rp) ^ (((d >> 5) & 3) << 3);
            unsigned int pv = (unsigned int)(unsigned short)va[u][i] |
                              ((unsigned int)(unsigned short)vb[u][i] << 16);
            *(unsigned int*)&Vt[d*72 + col] = pv;
        }
    }
    __syncthreads();   // Q/K0/V0 all staged (drains async16 queue)

    // Q A-frags live in registers for the whole K loop
    short8 af[4];
#pragma unroll
    for (int ks = 0; ks < 4; ++ks) {
        const int row = w*16 + m16;
        const int sl = (4*ks + quad) ^ ((row >> 1) & 7);
        af[ks] = *(const short8*)&Qs[row*128 + sl*8];
    }
    __syncthreads();   // all waves read Qs; Ks2[1] may now be overwritten

    f32x4 O[8] = {};
    float mrun[4] = {-1e30f,-1e30f,-1e30f,-1e30f};
    float lrun[4] = {0.f,0.f,0.f,0.f};
    unsigned short* Pw = Ps + w*16*72;

    for (int kt = 0; kt < SEQ/64; ++kt) {
        const int cur = kt & 1;
        const bool pre = (kt + 1 < SEQ/64);
        const long rowkv = rowb + (long)(kt + 1)*64;

        // ---- issue next tile's loads: V -> regs (consumed at iter end),
        //      K -> Ks2[cur^1] async (drained by the post-PV barrier) ----
        if (pre) {
#pragma unroll
            for (int u = 0; u < 2; ++u) {
                const int rp = u*16 + vrp;
                va[u] = *(const short8*)(qkv + (rowkv + 2*rp    )*LDQ + vc + vslot*8);
                vb[u] = *(const short8*)(qkv + (rowkv + 2*rp + 1)*LDQ + vc + vslot*8);
            }
#pragma unroll
            for (int u = 0; u < 4; ++u) {
                const int row = u*16 + rbase;
                const int c = slot ^ ((row >> 1) & 7);
                async16(qkv + (rowkv + row)*LDQ + kc + c*8, &Ks2[cur^1][u*2048 + w*512]);
            }
        }

        // ---- S = Q K^T (16 q-rows per wave x 64 j) ----
        f32x4 S[4];
#pragma unroll
        for (int ns = 0; ns < 4; ++ns) {
            f32x4 a = {0.f,0.f,0.f,0.f};
            const int row = ns*16 + m16;
            const int swr = (row >> 1) & 7;
#pragma unroll
            for (int ks = 0; ks < 4; ++ks) {
                const int sl = (4*ks + quad) ^ swr;
                const short8 bfr = *(const short8*)&Ks2[cur][row*128 + sl*8];
                a = __builtin_amdgcn_mfma_f32_16x16x32_bf16(af[ks], bfr, a, 0, 0, 0);
            }
#pragma unroll
            for (int r = 0; r < 4; ++r) a[r] *= 0.08838834764831845f; // 1/sqrt(128)
            S[ns] = a;
        }

        // ---- online softmax (lane holds rows quad*4+r, cols m16) ----
        float al[4], rs[4];
#pragma unroll
        for (int r = 0; r < 4; ++r) {
            float tm = fmaxf(fmaxf(S[0][r], S[1][r]), fmaxf(S[2][r], S[3][r]));
            tm = fmaxf(tm, __shfl_xor(tm, 1));
            tm = fmaxf(tm, __shfl_xor(tm, 2));
            tm = fmaxf(tm, __shfl_xor(tm, 4));
            tm = fmaxf(tm, __shfl_xor(tm, 8));
            const float mn = fmaxf(mrun[r], tm);
            al[r] = __expf(mrun[r] - mn);
            mrun[r] = mn;
            rs[r] = 0.f;
        }
#pragma unroll
        for (int ns = 0; ns < 4; ++ns)
#pragma unroll
            for (int r = 0; r < 4; ++r) {
                const float p = __expf(S[ns][r] - mrun[r]);
                rs[r] += p;
                Pw[(quad*4 + r)*72 + ns*16 + m16] = f2bf(p);
            }
#pragma unroll
        for (int r = 0; r < 4; ++r) {
            rs[r] += __shfl_xor(rs[r], 1);
            rs[r] += __shfl_xor(rs[r], 2);
            rs[r] += __shfl_xor(rs[r], 4);
            rs[r] += __shfl_xor(rs[r], 8);
            lrun[r] = lrun[r]*al[r] + rs[r];
        }
        // al[r]==1.0f exactly when the running max didn't grow -> skip is exact
        if (__any((al[0] != 1.f) | (al[1] != 1.f) | (al[2] != 1.f) | (al[3] != 1.f))) {
#pragma unroll
            for (int i = 0; i < 8; ++i)
#pragma unroll
                for (int r = 0; r < 4; ++r) O[i][r] *= al[r];
        }

        // ---- O += P V  (P via LDS: C-layout -> A-layout round trip) ----
#pragma unroll
        for (int ks2 = 0; ks2 < 2; ++ks2) {
            const short8 ap = *(const short8*)&Pw[m16*72 + ks2*32 + quad*8];
#pragma unroll
            for (int ds = 0; ds < 8; ++ds) {
                const int d = ds*16 + m16;
                const int jcol = (ks2*32 + quad*8) ^ (((d >> 5) & 3) << 3);
                const short8 bv = *(const short8*)&Vt[d*72 + jcol];
                O[ds] = __builtin_amdgcn_mfma_f32_16x16x32_bf16(ap, bv, O[ds], 0, 0, 0);
            }
        }

        __syncthreads();   // PV done (Vt free), drains Ks2[cur^1] prefetch
        if (pre) {
            // pack + write next V tile (regs were loaded at the top of this iter)
#pragma unroll
            for (int u = 0; u < 2; ++u) {
                const int rp = u*16 + vrp;
#pragma unroll
                for (int i = 0; i < 8; ++i) {
                    const int d = vslot*8 + i;
                    const int col = (2*rp) ^ (((d >> 5) & 3) << 3);
                    unsigned int pv = (unsigned int)(unsigned short)va[u][i] |
                                      ((unsigned int)(unsigned short)vb[u][i] << 16);
                    *(unsigned int*)&Vt[d*72 + col] = pv;
                }
            }
        }
        __syncthreads();   // Vt holds tile kt+1
    }

    // ---- normalize + write O over the Q columns ----
    float inv[4];
#pragma unroll
    for (int r = 0; r < 4; ++r) inv[r] = 1.0f / lrun[r];
#pragma unroll
    for (int ds = 0; ds < 8; ++ds)
#pragma unroll
        for (int r = 0; r < 4; ++r) {
            const long row = rowq + w*16 + quad*4 + r;
            qkv[row*LDQ + qc + ds*16 + m16] = f2bf(O[ds][r] * inv[r]);
        }
}

// ---------------------------------------------------------------------------
// LayerNorm over bf16 rows. OUTF32=1 writes fp32 (final output), else bf16.
// ---------------------------------------------------------------------------
template<int OUTF32>
__global__ __launch_bounds__(256)
void ln_bf16(const unsigned short* __restrict__ X, const float* __restrict__ g,
             const float* __restrict__ be, void* __restrict__ Y)
{
    __shared__ float r1[256], r2[256];
    const int t = threadIdx.x;
    const long row = blockIdx.x;
    const unsigned short* x = X + row*EMBED;
    float v[8];
    const short8 xv = *(const short8*)(x + t*8);
    float s = 0.f, s2 = 0.f;
#pragma unroll
    for (int i = 0; i < 8; ++i) {
        v[i] = bf2f((unsigned short)xv[i]);
        s += v[i]; s2 += v[i]*v[i];
    }
    r1[t] = s; r2[t] = s2;
    __syncthreads();
    for (int k = 128; k > 0; k >>= 1) {
        if (t < k) { r1[t] += r1[t+k]; r2[t] += r2[t+k]; }
        __syncthreads();
    }
    const float mu = r1[0] * (1.0f/EMBED);
    const float var = r2[0] * (1.0f/EMBED) - mu*mu;
    const float rstd = rsqrtf(var + 1e-5f);
    if (OUTF32) {
        float* y = (float*)Y + row*EMBED + t*8;
#pragma unroll
        for (int i = 0; i < 8; ++i) y[i] = (v[i]-mu)*rstd*g[t*8+i] + be[t*8+i];
    } else {
        unsigned short* y = (unsigned short*)Y + row*EMBED;
        short8 o;
#pragma unroll
        for (int i = 0; i < 8; ++i) o[i] = (short)f2bf((v[i]-mu)*rstd*g[t*8+i] + be[t*8+i]);
        *(short8*)(y + t*8) = o;
    }
}

// ---------------------------------------------------------------------------
// fp32 W[K][N] -> bf16 Wt[N][K] (transpose + convert), 32x32 LDS tiles
// ---------------------------------------------------------------------------
__global__ __launch_bounds__(256)
void cvt_transpose(const float* __restrict__ W, unsigned short* __restrict__ Wt, int K, int N)
{
    __shared__ unsigned short T[32][33];
    const int t = threadIdx.x;
    const long n0 = (long)blockIdx.x*32, k0 = (long)blockIdx.y*32;
    {
        const int r = t >> 3, c = (t & 7)*4;
        const float4 vv = *(const float4*)&W[(k0 + r)*N + n0 + c];
        T[r][c+0] = f2bf(vv.x); T[r][c+1] = f2bf(vv.y);
        T[r][c+2] = f2bf(vv.z); T[r][c+3] = f2bf(vv.w);
    }
    __syncthreads();
    const int rn = t >> 3, kk = (t & 7)*4;
    unsigned int p0 = (unsigned int)T[kk+0][rn] | ((unsigned int)T[kk+1][rn] << 16);
    unsigned int p1 = (unsigned int)T[kk+2][rn] | ((unsigned int)T[kk+3][rn] << 16);
    unsigned int* dst = (unsigned int*)&Wt[(n0 + rn)*K + k0 + kk];
    dst[0] = p0; dst[1] = p1;
}

__global__ __launch_bounds__(256)
void cvt_f32_bf16(const float* __restrict__ X, unsigned short* __restrict__ Y, long n)
{
    const long i = ((long)blockIdx.x*256 + threadIdx.x)*8;
    if (i >= n) return;
    const float4 a = *(const float4*)&X[i];
    const float4 b = *(const float4*)&X[i+4];
    short8 o;
    o[0]=(short)f2bf(a.x); o[1]=(short)f2bf(a.y); o[2]=(short)f2bf(a.z); o[3]=(short)f2bf(a.w);
    o[4]=(short)f2bf(b.x); o[5]=(short)f2bf(b.y); o[6]=(short)f2bf(b.z); o[7]=(short)f2bf(b.w);
    *(short8*)&Y[i] = o;
}

__global__ __launch_bounds__(256)
void concat_bias(const float* __restrict__ bq, const float* __restrict__ bk,
                 const float* __restrict__ bv, float* __restrict__ out)
{
    const int i = blockIdx.x*256 + threadIdx.x;
    if (i < 2048) out[i] = bq[i];
    else if (i < 4096) out[i] = bk[i-2048];
    else if (i < 6144) out[i] = bv[i-4096];
}

// ---------------------------------------------------------------------------
extern "C" void kernel_launch(void* const* d_in, const int* in_sizes, int n_in,
                              void* d_out, int out_size, void* d_ws, size_t ws_size,
                              hipStream_t stream)
{
    const float* x   = (const float*)d_in[0];
    const float* Wq  = (const float*)d_in[1];
    const float* bq  = (const float*)d_in[2];
    const float* Wk  = (const float*)d_in[3];
    const float* bk  = (const float*)d_in[4];
    const float* Wv  = (const float*)d_in[5];
    const float* bv  = (const float*)d_in[6];
    const float* Wo  = (const float*)d_in[7];
    const float* bo  = (const float*)d_in[8];
    const float* g1  = (const float*)d_in[9];
    const float* b1  = (const float*)d_in[10];
    const float* g2v = (const float*)d_in[11];
    const float* b2v = (const float*)d_in[12];
    const float* W1  = (const float*)d_in[13];
    const float* bf1 = (const float*)d_in[14];
    const float* W2  = (const float*)d_in[15];
    const float* bf2 = (const float*)d_in[16];
    float* out = (float*)d_out;

    // ---- workspace arena (byte offsets; total 184,573,952 B < 192 MiB) ----
    char* ws = (char*)d_ws;
    unsigned short* Wqkvt = (unsigned short*)(ws + 0);          // 25.2 MB [dead after GEMM1]
    unsigned short* Wot   = (unsigned short*)(ws + 25165824);   //  8.4 MB
    unsigned short* W1t   = (unsigned short*)(ws + 33554432);   // 33.6 MB
    unsigned short* W2t   = (unsigned short*)(ws + 67108864);   // 33.6 MB
    float*          bqkv  = (float*)         (ws + 100663296);  // 24 KB
    char* arenaA = ws + 100687872;                              // 67.1 MB arena
    unsigned short* xb   = (unsigned short*)(arenaA);           // 16.8 MB [cvt_x, GEMM1]
    unsigned short* qkv  = (unsigned short*)(arenaA + 16777216);// 50.3 MB [GEMM1, GEMM2]
    unsigned short* res1 = (unsigned short*)(arenaA);           // reuse xb slot [GEMM2, LN1]
    unsigned short* ff   = (unsigned short*)(arenaA);           // full arena [GEMM3, GEMM4]
    unsigned short* hb   = (unsigned short*)(ws + 167796736);   // 16.8 MB [LN1, GEMM4]
    unsigned short* res2 = (unsigned short*)(ws + 0);           // reuse Wqkvt slot [GEMM4, LN2]

    const dim3 blk(256);

    // weights: fp32 -> bf16 transposed
    cvt_transpose<<<dim3(64,64),  blk, 0, stream>>>(Wq, Wqkvt,             2048, 2048);
    cvt_transpose<<<dim3(64,64),  blk, 0, stream>>>(Wk, Wqkvt + 2048*2048, 2048, 2048);
    cvt_transpose<<<dim3(64,64),  blk, 0, stream>>>(Wv, Wqkvt + 2*2048*2048, 2048, 2048);
    cvt_transpose<<<dim3(64,64),  blk, 0, stream>>>(Wo, Wot, 2048, 2048);
    cvt_transpose<<<dim3(256,64), blk, 0, stream>>>(W1, W1t, 2048, 8192);
    cvt_transpose<<<dim3(64,256), blk, 0, stream>>>(W2, W2t, 8192, 2048);
    concat_bias<<<dim3(24), blk, 0, stream>>>(bq, bk, bv, bqkv);
    cvt_f32_bf16<<<dim3(4096), blk, 0, stream>>>(x, xb, (long)TOK*EMBED);

    // fused QKV projection -> qkv[4096][6144]
    gemm_bf16<0><<<dim3(48,32), blk, 0, stream>>>(xb, Wqkvt, bqkv, nullptr, qkv, TOK, 6144, 2048, 2048);
    // flash attention (O overwrites q-columns in-place)
    attn_flash<<<dim3(1024), blk, 0, stream>>>(qkv);
    // output projection + residual(x, fp32)
    gemm_bf16<1><<<dim3(16,32), blk, 0, stream>>>(qkv, Wot, bo, x, res1, TOK, 2048, 2048, 6144);
    ln_bf16<0><<<dim3(4096), blk, 0, stream>>>(res1, g1, b1, hb);
    // FFN
    gemm_bf16<2><<<dim3(64,32), blk, 0, stream>>>(hb, W1t, bf1, nullptr, ff, TOK, 8192, 2048, 2048);
    gemm_bf16<3><<<dim3(16,32), blk, 0, stream>>>(ff, W2t, bf2, hb, res2, TOK, 2048, 8192, 8192);
    ln_bf16<1><<<dim3(4096), blk, 0, stream>>>(res2, g2v, b2v, out);
}

// Round 4
// 956.024 us; speedup vs baseline: 1.0621x; 1.0132x over previous
//
#include <hip/hip_runtime.h>
#include <math.h>

#define EMBED 2048
#define DFF   8192
#define TOK   4096
#define SEQ   2048
#define HEADS 16
#define HD    128
#define LDQ   6144   // qkv row stride in elements (q|k|v concatenated)

typedef __attribute__((ext_vector_type(8))) short short8;
typedef __attribute__((ext_vector_type(4))) float f32x4;

__device__ __forceinline__ unsigned short f2bf(float f) {
    unsigned int u = __float_as_uint(f);
    return (unsigned short)((u + 0x7FFFu + ((u >> 16) & 1u)) >> 16);  // RNE
}
__device__ __forceinline__ float bf2f(unsigned short s) {
    return __uint_as_float(((unsigned int)s) << 16);
}
// 2^x via v_exp_f32 (native base-2). NOTE: name must not be __exp2f — glibc
// math.h declares that symbol and the collision breaks gfx950 compilation.
__device__ __forceinline__ float exp2_fast(float x) {
    return __builtin_amdgcn_exp2f(x);
}

// async global->LDS, 16B per lane. LDS dest = wave-uniform base + lane*16.
__device__ __forceinline__ void async16(const void* g, void* l) {
    __builtin_amdgcn_global_load_lds((const __attribute__((address_space(1))) void*)g,
                                     (__attribute__((address_space(3))) void*)l, 16, 0, 0);
}

// fast GELU (tanh form): v * sigmoid(1.5957691*(v + 0.044715 v^3)); |err|<~1e-3
__device__ __forceinline__ float gelu_fast(float v) {
    const float y = 1.5957691216057308f * (v + 0.044715f * v * v * v);
    return v / (1.0f + __expf(-y));
}

// ---------------------------------------------------------------------------
// bf16 MFMA GEMM: C[M,N](bf16) = A[M,K](bf16) @ Wt[N,K](bf16)^T + bias (+epi)
// 128x128 tile, BK=32, 256 thr = 4 waves (2x2 of 64x64), 16x16x32 MFMA.
// Single-barrier double-buffered K-loop. 2D grid, N-fastest (R3 mapping).
// Epilogue: acc -> LDS (f32, 2 passes) -> 16B coalesced bf16 stores.
// MODE: 0 plain, 1 +resid f32, 2 +GELU, 3 +resid bf16. Output always bf16.
// ---------------------------------------------------------------------------
template<int MODE>
__global__ __launch_bounds__(256, 2)
void gemm_bf16(const unsigned short* __restrict__ A, const unsigned short* __restrict__ B,
               const float* __restrict__ bias, const void* __restrict__ resid,
               unsigned short* __restrict__ C, int M, int N, int K, int lda)
{
    __shared__ __align__(16) float smemf[8448];          // 33.8 KB, multi-use
    unsigned short* As = (unsigned short*)smemf;         // As[2][4096] u16
    unsigned short* Bs = As + 8192;                      // Bs[2][4096] u16
    float* Cs = smemf;                                   // Cs[64][132] f32 (epilogue)

    const int t = threadIdx.x;
    const int w = t >> 6, l = t & 63;
    const int quad = l >> 4, m16 = l & 15;
    const long bm = (long)blockIdx.y * 128, bn = (long)blockIdx.x * 128;
    const int wr = (w >> 1)*64, wc = (w & 1)*64;   // this wave's 64x64 quadrant

    f32x4 acc[4][4] = {};

    const int srow = w*16 + (l >> 2);   // staging row (+u*64)
    const int sslot = l & 3;
    const unsigned short* Ag = A + (size_t)bm*lda;
    const unsigned short* Bg = B + (size_t)bn*K;

    // prologue: stage tile 0 -> buffer 0
#pragma unroll
    for (int u = 0; u < 2; ++u) {
        const int row = u*64 + srow;
        const int c = sslot ^ ((row >> 1) & 3);
        async16(Ag + (size_t)row*lda + c*8, &As[u*2048 + w*512]);
        async16(Bg + (size_t)row*K   + c*8, &Bs[u*2048 + w*512]);
    }

    const int iters = K >> 5;
    for (int it = 0; it < iters; ++it) {
        __syncthreads();   // drains tile-it glds (in flight since last iter)
        if (it + 1 < iters) {
            const int k0 = (it + 1) << 5;
            const int bo = ((it + 1) & 1) * 4096;
#pragma unroll
            for (int u = 0; u < 2; ++u) {
                const int row = u*64 + srow;
                const int c = sslot ^ ((row >> 1) & 3);
                async16(Ag + (size_t)row*lda + k0 + c*8, &As[bo + u*2048 + w*512]);
                async16(Bg + (size_t)row*K   + k0 + c*8, &Bs[bo + u*2048 + w*512]);
            }
        }
        const int co = (it & 1) * 4096;
        short8 af[4], bf[4];
#pragma unroll
        for (int s = 0; s < 4; ++s) {
            const int ra = wr + s*16 + m16;
            const int sla = quad ^ ((ra >> 1) & 3);
            af[s] = *(const short8*)&As[co + ra*32 + sla*8];
            const int rb = wc + s*16 + m16;
            const int slb = quad ^ ((rb >> 1) & 3);
            bf[s] = *(const short8*)&Bs[co + rb*32 + slb*8];
        }
#pragma unroll
        for (int ms = 0; ms < 4; ++ms)
#pragma unroll
            for (int ns = 0; ns < 4; ++ns)
                acc[ms][ns] = __builtin_amdgcn_mfma_f32_16x16x32_bf16(af[ms], bf[ns], acc[ms][ns], 0, 0, 0);
    }

    // ---- epilogue via LDS: 2 passes of 64 rows ----
    const int ecol = (t & 15) * 8;          // this lane's 8 output cols
    float bias8[8];
#pragma unroll
    for (int i = 0; i < 8; ++i) bias8[i] = bias[bn + ecol + i];

#pragma unroll
    for (int pass = 0; pass < 2; ++pass) {
        __syncthreads();   // prior LDS use (K-loop buffers / previous pass) done
        if ((w >> 1) == pass) {   // waves owning rows [pass*64, pass*64+64) stage
#pragma unroll
            for (int ms = 0; ms < 4; ++ms)
#pragma unroll
                for (int ns = 0; ns < 4; ++ns)
#pragma unroll
                    for (int r = 0; r < 4; ++r)
                        Cs[(ms*16 + quad*4 + r)*132 + wc + ns*16 + m16] = acc[ms][ns][r];
        }
        __syncthreads();
#pragma unroll
        for (int j = 0; j < 4; ++j) {
            const int row = j*16 + (t >> 4);
            float v[8];
            *(f32x4*)&v[0] = *(const f32x4*)&Cs[row*132 + ecol];
            *(f32x4*)&v[4] = *(const f32x4*)&Cs[row*132 + ecol + 4];
            const long gr = bm + pass*64 + row;
            const long go = gr*N + bn + ecol;
            float r8[8];
            if (MODE == 1) {
                *(f32x4*)&r8[0] = *(const f32x4*)((const float*)resid + go);
                *(f32x4*)&r8[4] = *(const f32x4*)((const float*)resid + go + 4);
            }
            short8 rb16;
            if (MODE == 3) rb16 = *(const short8*)((const unsigned short*)resid + go);
            short8 o;
#pragma unroll
            for (int i = 0; i < 8; ++i) {
                float y = v[i] + bias8[i];
                if (MODE == 1) y += r8[i];
                if (MODE == 3) y += bf2f((unsigned short)rb16[i]);
                if (MODE == 2) y = gelu_fast(y);
                o[i] = (short)f2bf(y);
            }
            *(short8*)&C[go] = o;
        }
    }
}

// ---------------------------------------------------------------------------
// Flash attention, bf16 MFMA. One block = (b, h, 64-row Q tile). 256 thr.
// qkv layout: [4096 rows][6144] bf16 = q|k|v, head h at cols h*128 (+0/2048/4096).
// O is written in-place over the Q columns (only this block reads them).
//
// R6 structure (R5 post-mortem: FETCH 136 MB vs ~48 MB ideal -> K/V thrashes
// the per-XCD L2 because q-tiles of one head stripe across all 8 XCDs; plus
// 2 barriers/iter with a serial V-pack between them). R8 = R6 with the
// __exp2f -> __builtin_amdgcn_exp2f fix (glibc math.h symbol collision).
//  - T1 XCD-chunked swizzle: dispatch d -> XCD d&7 (round-robin HW mapping);
//    give each XCD 4 whole heads (32 q-tiles each) so its ~64 resident
//    blocks share 2 heads' K/V = 2 MiB < 4 MiB L2. Bijective remap.
//  - Vt double-buffered (+18 KiB LDS = 78,848 B total, still 2 blocks/CU):
//    V-pack for kt+1 runs BEFORE PV (waits only its own loads; K glds stay
//    in flight) -> ONE barrier per iteration covers all hazards.
//  - base-2 softmax: log2(e) folded into the QK scale, v_exp_f32 everywhere
//    (natively 2^x; saves 20 wave-wide v_mul per iter).
//  - O-rescale skipped when running max didn't grow (al==1.0 exact).
// ---------------------------------------------------------------------------
__global__ __launch_bounds__(256, 2)
void attn_flash(unsigned short* __restrict__ qkv)
{
    __shared__ unsigned short Ks2[2][64*128]; // K dbuf; buf1 doubles as Q staging
    __shared__ unsigned short Vt2[2][128*72]; // V^T dbuf [d][j], col j ^ (((d>>5)&3)<<3)
    __shared__ unsigned short Ps[4*16*72];    // per-wave P scratch

    const int t = threadIdx.x;
    const int w = t >> 6, l = t & 63;
    const int quad = l >> 4, m16 = l & 15;

    // XCD-chunked decode: 1024 dispatches, XCD = d&7, 128 blocks/XCD = 4 heads
    const int dd = blockIdx.x;
    const int bh = (dd & 7)*4 + ((dd >> 3) >> 5);
    const int qt = (dd >> 3) & 31;
    const int b = bh >> 4, h = bh & 15;

    const long rowq = (long)b*SEQ + qt*64;
    const long rowb = (long)b*SEQ;
    const int qc = h*HD;
    const int kc = EMBED + h*HD;
    const int vc = 2*EMBED + h*HD;

    const int rbase = w*4 + (l >> 4);   // K/Q staging row base
    const int slot  = l & 15;           // K/Q staging 16B slot
    const int vslot = t & 15;           // V staging d-slot
    const int vrp   = t >> 4;           // V staging row-pair base

    unsigned short* Qs = Ks2[1];

    // ---- prologue: V0 -> regs (issued first = oldest vmcnt entries),
    //      Q -> Qs(=Ks2[1]) and K0 -> Ks2[0] async ----
    short8 va[2], vb[2];
#pragma unroll
    for (int u = 0; u < 2; ++u) {
        const int rp = u*16 + vrp;
        va[u] = *(const short8*)(qkv + (rowb + 2*rp    )*LDQ + vc + vslot*8);
        vb[u] = *(const short8*)(qkv + (rowb + 2*rp + 1)*LDQ + vc + vslot*8);
    }
#pragma unroll
    for (int u = 0; u < 4; ++u) {
        const int row = u*16 + rbase;
        const int c = slot ^ ((row >> 1) & 7);
        async16(qkv + (rowq + row)*LDQ + qc + c*8, Qs + u*2048 + w*512);
        async16(qkv + (rowb + row)*LDQ + kc + c*8, &Ks2[0][u*2048 + w*512]);
    }
    // write V0 (waits vmcnt only down to the va/vb loads; Q/K glds stay in flight)
#pragma unroll
    for (int u = 0; u < 2; ++u) {
        const int rp = u*16 + vrp;
#pragma unroll
        for (int i = 0; i < 8; ++i) {
            const int dv = vslot*8 + i;
            const int col = (2*rp) ^ (((dv >> 5) & 3) << 3);
            unsigned int pv = (unsigned int)(unsigned short)va[u][i] |
                              ((unsigned int)(unsigned short)vb[u][i] << 16);
            *(unsigned int*)&Vt2[0][dv*72 + col] = pv;
        }
    }
    __syncthreads();   // Q/K0/V0 all staged (drains async16 queue)

    // Q A-frags live in registers for the whole K loop
    short8 af[4];
#pragma unroll
    for (int ks = 0; ks < 4; ++ks) {
        const int row = w*16 + m16;
        const int sl = (4*ks + quad) ^ ((row >> 1) & 7);
        af[ks] = *(const short8*)&Qs[row*128 + sl*8];
    }
    __syncthreads();   // all waves read Qs; Ks2[1] may now be overwritten

    f32x4 O[8] = {};
    float mrun[4] = {-1e30f,-1e30f,-1e30f,-1e30f};
    float lrun[4] = {0.f,0.f,0.f,0.f};
    unsigned short* Pw = Ps + w*16*72;
    const float SC = 0.08838834764831845f * 1.4426950408889634f; // 1/sqrt(128) * log2(e)

    for (int kt = 0; kt < SEQ/64; ++kt) {
        const int cur = kt & 1;
        const bool pre = (kt + 1 < SEQ/64);
        const long rowkv = rowb + (long)(kt + 1)*64;

        // ---- issue next tile's loads: V -> regs (packed later this iter),
        //      K -> Ks2[cur^1] async (drained by the end-of-iter barrier) ----
        if (pre) {
#pragma unroll
            for (int u = 0; u < 2; ++u) {
                const int rp = u*16 + vrp;
                va[u] = *(const short8*)(qkv + (rowkv + 2*rp    )*LDQ + vc + vslot*8);
                vb[u] = *(const short8*)(qkv + (rowkv + 2*rp + 1)*LDQ + vc + vslot*8);
            }
#pragma unroll
            for (int u = 0; u < 4; ++u) {
                const int row = u*16 + rbase;
                const int c = slot ^ ((row >> 1) & 7);
                async16(qkv + (rowkv + row)*LDQ + kc + c*8, &Ks2[cur^1][u*2048 + w*512]);
            }
        }

        // ---- S = Q K^T (16 q-rows per wave x 64 j), log2 domain ----
        f32x4 S[4];
#pragma unroll
        for (int ns = 0; ns < 4; ++ns) {
            f32x4 a = {0.f,0.f,0.f,0.f};
            const int row = ns*16 + m16;
            const int swr = (row >> 1) & 7;
#pragma unroll
            for (int ks = 0; ks < 4; ++ks) {
                const int sl = (4*ks + quad) ^ swr;
                const short8 bfr = *(const short8*)&Ks2[cur][row*128 + sl*8];
                a = __builtin_amdgcn_mfma_f32_16x16x32_bf16(af[ks], bfr, a, 0, 0, 0);
            }
#pragma unroll
            for (int r = 0; r < 4; ++r) a[r] *= SC;
            S[ns] = a;
        }

        // ---- online softmax, base 2 (lane holds rows quad*4+r, cols m16) ----
        float al[4], rs[4];
#pragma unroll
        for (int r = 0; r < 4; ++r) {
            float tm = fmaxf(fmaxf(S[0][r], S[1][r]), fmaxf(S[2][r], S[3][r]));
            tm = fmaxf(tm, __shfl_xor(tm, 1));
            tm = fmaxf(tm, __shfl_xor(tm, 2));
            tm = fmaxf(tm, __shfl_xor(tm, 4));
            tm = fmaxf(tm, __shfl_xor(tm, 8));
            const float mn = fmaxf(mrun[r], tm);
            al[r] = exp2_fast(mrun[r] - mn);
            mrun[r] = mn;
            rs[r] = 0.f;
        }
#pragma unroll
        for (int ns = 0; ns < 4; ++ns)
#pragma unroll
            for (int r = 0; r < 4; ++r) {
                const float p = exp2_fast(S[ns][r] - mrun[r]);
                rs[r] += p;
                Pw[(quad*4 + r)*72 + ns*16 + m16] = f2bf(p);
            }
#pragma unroll
        for (int r = 0; r < 4; ++r) {
            rs[r] += __shfl_xor(rs[r], 1);
            rs[r] += __shfl_xor(rs[r], 2);
            rs[r] += __shfl_xor(rs[r], 4);
            rs[r] += __shfl_xor(rs[r], 8);
            lrun[r] = lrun[r]*al[r] + rs[r];
        }
        // al[r]==1.0f exactly when the running max didn't grow -> skip is exact
        if (__any((al[0] != 1.f) | (al[1] != 1.f) | (al[2] != 1.f) | (al[3] != 1.f))) {
#pragma unroll
            for (int i = 0; i < 8; ++i)
#pragma unroll
                for (int r = 0; r < 4; ++r) O[i][r] *= al[r];
        }

        // ---- pack next V tile -> Vt2[cur^1] (other buffer; last read at the
        //      end of iter kt-1, so safe after that barrier). Waits vmcnt only
        //      down to the va/vb loads; K glds stay in flight. ----
        if (pre) {
#pragma unroll
            for (int u = 0; u < 2; ++u) {
                const int rp = u*16 + vrp;
#pragma unroll
                for (int i = 0; i < 8; ++i) {
                    const int dv = vslot*8 + i;
                    const int col = (2*rp) ^ (((dv >> 5) & 3) << 3);
                    unsigned int pv = (unsigned int)(unsigned short)va[u][i] |
                                      ((unsigned int)(unsigned short)vb[u][i] << 16);
                    *(unsigned int*)&Vt2[cur^1][dv*72 + col] = pv;
                }
            }
        }

        // ---- O += P V  (P via LDS: C-layout -> A-layout round trip) ----
#pragma unroll
        for (int ks2 = 0; ks2 < 2; ++ks2) {
            const short8 ap = *(const short8*)&Pw[m16*72 + ks2*32 + quad*8];
#pragma unroll
            for (int ds = 0; ds < 8; ++ds) {
                const int dv = ds*16 + m16;
                const int jcol = (ks2*32 + quad*8) ^ (((dv >> 5) & 3) << 3);
                const short8 bv = *(const short8*)&Vt2[cur][dv*72 + jcol];
                O[ds] = __builtin_amdgcn_mfma_f32_16x16x32_bf16(ap, bv, O[ds], 0, 0, 0);
            }
        }

        // single barrier: drains K glds (Ks2[cur^1] ready), makes Vt2[cur^1]
        // writes visible, and fences all waves' reads of Ks2[cur]/Vt2[cur]
        // before iteration kt+1 overwrites them.
        __syncthreads();
    }

    // ---- normalize + write O over the Q columns ----
    float inv[4];
#pragma unroll
    for (int r = 0; r < 4; ++r) inv[r] = 1.0f / lrun[r];
#pragma unroll
    for (int ds = 0; ds < 8; ++ds)
#pragma unroll
        for (int r = 0; r < 4; ++r) {
            const long row = rowq + w*16 + quad*4 + r;
            qkv[row*LDQ + qc + ds*16 + m16] = f2bf(O[ds][r] * inv[r]);
        }
}

// ---------------------------------------------------------------------------
// LayerNorm over bf16 rows. OUTF32=1 writes fp32 (final output), else bf16.
// ---------------------------------------------------------------------------
template<int OUTF32>
__global__ __launch_bounds__(256)
void ln_bf16(const unsigned short* __restrict__ X, const float* __restrict__ g,
             const float* __restrict__ be, void* __restrict__ Y)
{
    __shared__ float r1[256], r2[256];
    const int t = threadIdx.x;
    const long row = blockIdx.x;
    const unsigned short* x = X + row*EMBED;
    float v[8];
    const short8 xv = *(const short8*)(x + t*8);
    float s = 0.f, s2 = 0.f;
#pragma unroll
    for (int i = 0; i < 8; ++i) {
        v[i] = bf2f((unsigned short)xv[i]);
        s += v[i]; s2 += v[i]*v[i];
    }
    r1[t] = s; r2[t] = s2;
    __syncthreads();
    for (int k = 128; k > 0; k >>= 1) {
        if (t < k) { r1[t] += r1[t+k]; r2[t] += r2[t+k]; }
        __syncthreads();
    }
    const float mu = r1[0] * (1.0f/EMBED);
    const float var = r2[0] * (1.0f/EMBED) - mu*mu;
    const float rstd = rsqrtf(var + 1e-5f);
    if (OUTF32) {
        float* y = (float*)Y + row*EMBED + t*8;
#pragma unroll
        for (int i = 0; i < 8; ++i) y[i] = (v[i]-mu)*rstd*g[t*8+i] + be[t*8+i];
    } else {
        unsigned short* y = (unsigned short*)Y + row*EMBED;
        short8 o;
#pragma unroll
        for (int i = 0; i < 8; ++i) o[i] = (short)f2bf((v[i]-mu)*rstd*g[t*8+i] + be[t*8+i]);
        *(short8*)(y + t*8) = o;
    }
}

// ---------------------------------------------------------------------------
// fp32 W[K][N] -> bf16 Wt[N][K] (transpose + convert), 32x32 LDS tiles
// ---------------------------------------------------------------------------
__global__ __launch_bounds__(256)
void cvt_transpose(const float* __restrict__ W, unsigned short* __restrict__ Wt, int K, int N)
{
    __shared__ unsigned short T[32][33];
    const int t = threadIdx.x;
    const long n0 = (long)blockIdx.x*32, k0 = (long)blockIdx.y*32;
    {
        const int r = t >> 3, c = (t & 7)*4;
        const float4 vv = *(const float4*)&W[(k0 + r)*N + n0 + c];
        T[r][c+0] = f2bf(vv.x); T[r][c+1] = f2bf(vv.y);
        T[r][c+2] = f2bf(vv.z); T[r][c+3] = f2bf(vv.w);
    }
    __syncthreads();
    const int rn = t >> 3, kk = (t & 7)*4;
    unsigned int p0 = (unsigned int)T[kk+0][rn] | ((unsigned int)T[kk+1][rn] << 16);
    unsigned int p1 = (unsigned int)T[kk+2][rn] | ((unsigned int)T[kk+3][rn] << 16);
    unsigned int* dst = (unsigned int*)&Wt[(n0 + rn)*K + k0 + kk];
    dst[0] = p0; dst[1] = p1;
}

__global__ __launch_bounds__(256)
void cvt_f32_bf16(const float* __restrict__ X, unsigned short* __restrict__ Y, long n)
{
    const long i = ((long)blockIdx.x*256 + threadIdx.x)*8;
    if (i >= n) return;
    const float4 a = *(const float4*)&X[i];
    const float4 b = *(const float4*)&X[i+4];
    short8 o;
    o[0]=(short)f2bf(a.x); o[1]=(short)f2bf(a.y); o[2]=(short)f2bf(a.z); o[3]=(short)f2bf(a.w);
    o[4]=(short)f2bf(b.x); o[5]=(short)f2bf(b.y); o[6]=(short)f2bf(b.z); o[7]=(short)f2bf(b.w);
    *(short8*)&Y[i] = o;
}

__global__ __launch_bounds__(256)
void concat_bias(const float* __restrict__ bq, const float* __restrict__ bk,
                 const float* __restrict__ bv, float* __restrict__ out)
{
    const int i = blockIdx.x*256 + threadIdx.x;
    if (i < 2048) out[i] = bq[i];
    else if (i < 4096) out[i] = bk[i-2048];
    else if (i < 6144) out[i] = bv[i-4096];
}

// ---------------------------------------------------------------------------
extern "C" void kernel_launch(void* const* d_in, const int* in_sizes, int n_in,
                              void* d_out, int out_size, void* d_ws, size_t ws_size,
                              hipStream_t stream)
{
    const float* x   = (const float*)d_in[0];
    const float* Wq  = (const float*)d_in[1];
    const float* bq  = (const float*)d_in[2];
    const float* Wk  = (const float*)d_in[3];
    const float* bk  = (const float*)d_in[4];
    const float* Wv  = (const float*)d_in[5];
    const float* bv  = (const float*)d_in[6];
    const float* Wo  = (const float*)d_in[7];
    const float* bo  = (const float*)d_in[8];
    const float* g1  = (const float*)d_in[9];
    const float* b1  = (const float*)d_in[10];
    const float* g2v = (const float*)d_in[11];
    const float* b2v = (const float*)d_in[12];
    const float* W1  = (const float*)d_in[13];
    const float* bf1 = (const float*)d_in[14];
    const float* W2  = (const float*)d_in[15];
    const float* bf2 = (const float*)d_in[16];
    float* out = (float*)d_out;

    // ---- workspace arena (byte offsets; total 184,573,952 B < 192 MiB) ----
    char* ws = (char*)d_ws;
    unsigned short* Wqkvt = (unsigned short*)(ws + 0);          // 25.2 MB [dead after GEMM1]
    unsigned short* Wot   = (unsigned short*)(ws + 25165824);   //  8.4 MB
    unsigned short* W1t   = (unsigned short*)(ws + 33554432);   // 33.6 MB
    unsigned short* W2t   = (unsigned short*)(ws + 67108864);   // 33.6 MB
    float*          bqkv  = (float*)         (ws + 100663296);  // 24 KB
    char* arenaA = ws + 100687872;                              // 67.1 MB arena
    unsigned short* xb   = (unsigned short*)(arenaA);           // 16.8 MB [cvt_x, GEMM1]
    unsigned short* qkv  = (unsigned short*)(arenaA + 16777216);// 50.3 MB [GEMM1, GEMM2]
    unsigned short* res1 = (unsigned short*)(arenaA);           // reuse xb slot [GEMM2, LN1]
    unsigned short* ff   = (unsigned short*)(arenaA);           // full arena [GEMM3, GEMM4]
    unsigned short* hb   = (unsigned short*)(ws + 167796736);   // 16.8 MB [LN1, GEMM4]
    unsigned short* res2 = (unsigned short*)(ws + 0);           // reuse Wqkvt slot [GEMM4, LN2]

    const dim3 blk(256);

    // weights: fp32 -> bf16 transposed
    cvt_transpose<<<dim3(64,64),  blk, 0, stream>>>(Wq, Wqkvt,             2048, 2048);
    cvt_transpose<<<dim3(64,64),  blk, 0, stream>>>(Wk, Wqkvt + 2048*2048, 2048, 2048);
    cvt_transpose<<<dim3(64,64),  blk, 0, stream>>>(Wv, Wqkvt + 2*2048*2048, 2048, 2048);
    cvt_transpose<<<dim3(64,64),  blk, 0, stream>>>(Wo, Wot, 2048, 2048);
    cvt_transpose<<<dim3(256,64), blk, 0, stream>>>(W1, W1t, 2048, 8192);
    cvt_transpose<<<dim3(64,256), blk, 0, stream>>>(W2, W2t, 8192, 2048);
    concat_bias<<<dim3(24), blk, 0, stream>>>(bq, bk, bv, bqkv);
    cvt_f32_bf16<<<dim3(4096), blk, 0, stream>>>(x, xb, (long)TOK*EMBED);

    // fused QKV projection -> qkv[4096][6144]
    gemm_bf16<0><<<dim3(48,32), blk, 0, stream>>>(xb, Wqkvt, bqkv, nullptr, qkv, TOK, 6144, 2048, 2048);
    // flash attention (O overwrites q-columns in-place)
    attn_flash<<<dim3(1024), blk, 0, stream>>>(qkv);
    // output projection + residual(x, fp32)
    gemm_bf16<1><<<dim3(16,32), blk, 0, stream>>>(qkv, Wot, bo, x, res1, TOK, 2048, 2048, 6144);
    ln_bf16<0><<<dim3(4096), blk, 0, stream>>>(res1, g1, b1, hb);
    // FFN
    gemm_bf16<2><<<dim3(64,32), blk, 0, stream>>>(hb, W1t, bf1, nullptr, ff, TOK, 8192, 2048, 2048);
    gemm_bf16<3><<<dim3(16,32), blk, 0, stream>>>(ff, W2t, bf2, hb, res2, TOK, 2048, 8192, 8192);
    ln_bf16<1><<<dim3(4096), blk, 0, stream>>>(res2, g2v, b2v, out);
}

// Round 5
// 929.838 us; speedup vs baseline: 1.0920x; 1.0282x over previous
//
#include <hip/hip_runtime.h>
#include <math.h>

#define EMBED 2048
#define DFF   8192
#define TOK   4096
#define SEQ   2048
#define HEADS 16
#define HD    128
#define LDQ   6144   // qkv row stride in elements (q|k|v concatenated)

typedef __attribute__((ext_vector_type(8))) short short8;
typedef __attribute__((ext_vector_type(4))) float f32x4;

__device__ __forceinline__ unsigned short f2bf(float f) {
    unsigned int u = __float_as_uint(f);
    return (unsigned short)((u + 0x7FFFu + ((u >> 16) & 1u)) >> 16);  // RNE
}
__device__ __forceinline__ float bf2f(unsigned short s) {
    return __uint_as_float(((unsigned int)s) << 16);
}
// 2^x via v_exp_f32 (native base-2). NOTE: name must not be __exp2f — glibc
// math.h declares that symbol and the collision breaks gfx950 compilation.
__device__ __forceinline__ float exp2_fast(float x) {
    return __builtin_amdgcn_exp2f(x);
}

// async global->LDS, 16B per lane. LDS dest = wave-uniform base + lane*16.
__device__ __forceinline__ void async16(const void* g, void* l) {
    __builtin_amdgcn_global_load_lds((const __attribute__((address_space(1))) void*)g,
                                     (__attribute__((address_space(3))) void*)l, 16, 0, 0);
}

// fast GELU (tanh form): v * sigmoid(1.5957691*(v + 0.044715 v^3)); |err|<~1e-3
__device__ __forceinline__ float gelu_fast(float v) {
    const float y = 1.5957691216057308f * (v + 0.044715f * v * v * v);
    return v / (1.0f + __expf(-y));
}

// ---------------------------------------------------------------------------
// bf16 MFMA GEMM: C[M,N](bf16) = A[M,K](bf16) @ Wt[N,K](bf16)^T + bias (+epi)
// 128x128 tile, BK=32, 256 thr = 4 waves (2x2 of 64x64), 16x16x32 MFMA.
// Single-barrier double-buffered K-loop. 2D grid, N-fastest (R3 mapping).
// Epilogue: acc -> LDS (f32, 2 passes) -> 16B coalesced bf16 stores.
// MODE: 0 plain, 1 +resid f32, 2 +GELU, 3 +resid bf16. Output always bf16.
// ---------------------------------------------------------------------------
template<int MODE>
__global__ __launch_bounds__(256, 2)
void gemm_bf16(const unsigned short* __restrict__ A, const unsigned short* __restrict__ B,
               const float* __restrict__ bias, const void* __restrict__ resid,
               unsigned short* __restrict__ C, int M, int N, int K, int lda)
{
    __shared__ __align__(16) float smemf[8448];          // 33.8 KB, multi-use
    unsigned short* As = (unsigned short*)smemf;         // As[2][4096] u16
    unsigned short* Bs = As + 8192;                      // Bs[2][4096] u16
    float* Cs = smemf;                                   // Cs[64][132] f32 (epilogue)

    const int t = threadIdx.x;
    const int w = t >> 6, l = t & 63;
    const int quad = l >> 4, m16 = l & 15;
    const long bm = (long)blockIdx.y * 128, bn = (long)blockIdx.x * 128;
    const int wr = (w >> 1)*64, wc = (w & 1)*64;   // this wave's 64x64 quadrant

    f32x4 acc[4][4] = {};

    const int srow = w*16 + (l >> 2);   // staging row (+u*64)
    const int sslot = l & 3;
    const unsigned short* Ag = A + (size_t)bm*lda;
    const unsigned short* Bg = B + (size_t)bn*K;

    // prologue: stage tile 0 -> buffer 0
#pragma unroll
    for (int u = 0; u < 2; ++u) {
        const int row = u*64 + srow;
        const int c = sslot ^ ((row >> 1) & 3);
        async16(Ag + (size_t)row*lda + c*8, &As[u*2048 + w*512]);
        async16(Bg + (size_t)row*K   + c*8, &Bs[u*2048 + w*512]);
    }

    const int iters = K >> 5;
    for (int it = 0; it < iters; ++it) {
        __syncthreads();   // drains tile-it glds (in flight since last iter)
        if (it + 1 < iters) {
            const int k0 = (it + 1) << 5;
            const int bo = ((it + 1) & 1) * 4096;
#pragma unroll
            for (int u = 0; u < 2; ++u) {
                const int row = u*64 + srow;
                const int c = sslot ^ ((row >> 1) & 3);
                async16(Ag + (size_t)row*lda + k0 + c*8, &As[bo + u*2048 + w*512]);
                async16(Bg + (size_t)row*K   + k0 + c*8, &Bs[bo + u*2048 + w*512]);
            }
        }
        const int co = (it & 1) * 4096;
        short8 af[4], bf[4];
#pragma unroll
        for (int s = 0; s < 4; ++s) {
            const int ra = wr + s*16 + m16;
            const int sla = quad ^ ((ra >> 1) & 3);
            af[s] = *(const short8*)&As[co + ra*32 + sla*8];
            const int rb = wc + s*16 + m16;
            const int slb = quad ^ ((rb >> 1) & 3);
            bf[s] = *(const short8*)&Bs[co + rb*32 + slb*8];
        }
#pragma unroll
        for (int ms = 0; ms < 4; ++ms)
#pragma unroll
            for (int ns = 0; ns < 4; ++ns)
                acc[ms][ns] = __builtin_amdgcn_mfma_f32_16x16x32_bf16(af[ms], bf[ns], acc[ms][ns], 0, 0, 0);
    }

    // ---- epilogue via LDS: 2 passes of 64 rows ----
    const int ecol = (t & 15) * 8;          // this lane's 8 output cols
    float bias8[8];
#pragma unroll
    for (int i = 0; i < 8; ++i) bias8[i] = bias[bn + ecol + i];

#pragma unroll
    for (int pass = 0; pass < 2; ++pass) {
        __syncthreads();   // prior LDS use (K-loop buffers / previous pass) done
        if ((w >> 1) == pass) {   // waves owning rows [pass*64, pass*64+64) stage
#pragma unroll
            for (int ms = 0; ms < 4; ++ms)
#pragma unroll
                for (int ns = 0; ns < 4; ++ns)
#pragma unroll
                    for (int r = 0; r < 4; ++r)
                        Cs[(ms*16 + quad*4 + r)*132 + wc + ns*16 + m16] = acc[ms][ns][r];
        }
        __syncthreads();
#pragma unroll
        for (int j = 0; j < 4; ++j) {
            const int row = j*16 + (t >> 4);
            float v[8];
            *(f32x4*)&v[0] = *(const f32x4*)&Cs[row*132 + ecol];
            *(f32x4*)&v[4] = *(const f32x4*)&Cs[row*132 + ecol + 4];
            const long gr = bm + pass*64 + row;
            const long go = gr*N + bn + ecol;
            float r8[8];
            if (MODE == 1) {
                *(f32x4*)&r8[0] = *(const f32x4*)((const float*)resid + go);
                *(f32x4*)&r8[4] = *(const f32x4*)((const float*)resid + go + 4);
            }
            short8 rb16;
            if (MODE == 3) rb16 = *(const short8*)((const unsigned short*)resid + go);
            short8 o;
#pragma unroll
            for (int i = 0; i < 8; ++i) {
                float y = v[i] + bias8[i];
                if (MODE == 1) y += r8[i];
                if (MODE == 3) y += bf2f((unsigned short)rb16[i]);
                if (MODE == 2) y = gelu_fast(y);
                o[i] = (short)f2bf(y);
            }
            *(short8*)&C[go] = o;
        }
    }
}

// ---------------------------------------------------------------------------
// Flash attention, bf16 MFMA. One block = (b, h, 128-row Q tile). 256 thr.
// qkv layout: [4096 rows][6144] bf16 = q|k|v, head h at cols h*128 (+0/2048/4096).
// O is written in-place over the Q columns (only this block reads them).
//
// R9: QBLK 64 -> 128 (R8 post-mortem: LDS-throughput-bound — ~61% LDS pipe
// occupancy + 23% bank-conflict cycles; MFMA 13.5%, VALU 29%, HBM 2.5% all
// idle). Each wave owns 32 q-rows (two 16-row halves): one K-fragment
// ds_read feeds TWO MFMAs (dual-accumulate), halving K-read cost per FLOP;
// staging/V-pack/barrier/prefetch amortize over 2x FLOP. Per-qh
// softmax->P-write->PV reuses the same per-wave Pw scratch (same-wave LDS
// ordering), so LDS stays 78,848 B = 2 blocks/CU. Grid 512 = all resident.
// Q (128x128 = 32 KB) stages through a Vt2 overlay (3-barrier prologue).
// Keeps R8 wins: XCD-chunked swizzle (FETCH 139->24.6 MB), single-barrier
// iteration, base-2 softmax, exact rescale-skip.
// ---------------------------------------------------------------------------
__global__ __launch_bounds__(256, 2)
void attn_flash(unsigned short* __restrict__ qkv)
{
    __shared__ unsigned short Ks2[2][64*128]; // K dbuf (32,768 B)
    __shared__ unsigned short Vt2[2][128*72]; // V^T dbuf [d][j] (36,864 B); Q-staging overlay
    __shared__ unsigned short Ps[4*16*72];    // per-wave P scratch (9,216 B)

    const int t = threadIdx.x;
    const int w = t >> 6, l = t & 63;
    const int quad = l >> 4, m16 = l & 15;

    // XCD-chunked decode: 512 dispatches, XCD = d&7, 64 blocks/XCD = 4 bh's
    const int dd = blockIdx.x;
    const int bh = (dd & 7)*4 + ((dd >> 3) >> 4);  // 0..31
    const int qt = (dd >> 3) & 15;                 // 0..15 (128-row tiles)
    const int b = bh >> 4, h = bh & 15;

    const long rowq = (long)b*SEQ + qt*128;
    const long rowb = (long)b*SEQ;
    const int qc = h*HD;
    const int kc = EMBED + h*HD;
    const int vc = 2*EMBED + h*HD;

    const int rbase = w*4 + (l >> 4);   // K/Q staging row base
    const int slot  = l & 15;           // K/Q staging 16B slot
    const int vslot = t & 15;           // V staging d-slot
    const int vrp   = t >> 4;           // V staging row-pair base

    unsigned short* QsOv = (unsigned short*)Vt2;   // Q overlay: 128*128*2 = 32 KB <= 36,864 B

    // ---- prologue: V0 -> regs (oldest vmcnt entries), Q -> QsOv, K0 -> Ks2[0] ----
    short8 va[2], vb[2];
#pragma unroll
    for (int u = 0; u < 2; ++u) {
        const int rp = u*16 + vrp;
        va[u] = *(const short8*)(qkv + (rowb + 2*rp    )*LDQ + vc + vslot*8);
        vb[u] = *(const short8*)(qkv + (rowb + 2*rp + 1)*LDQ + vc + vslot*8);
    }
#pragma unroll
    for (int u = 0; u < 8; ++u) {   // Q: 128 rows
        const int row = u*16 + rbase;
        const int c = slot ^ ((row >> 1) & 7);
        async16(qkv + (rowq + row)*LDQ + qc + c*8, QsOv + u*2048 + w*512);
    }
#pragma unroll
    for (int u = 0; u < 4; ++u) {   // K0: 64 rows
        const int row = u*16 + rbase;
        const int c = slot ^ ((row >> 1) & 7);
        async16(qkv + (rowb + row)*LDQ + kc + c*8, &Ks2[0][u*2048 + w*512]);
    }
    __syncthreads();   // Q + K0 staged

    // Q A-frags: wave w owns q-rows [w*32, w*32+32), two 16-row halves
    short8 af[2][4];
#pragma unroll
    for (int qh = 0; qh < 2; ++qh)
#pragma unroll
        for (int ks = 0; ks < 4; ++ks) {
            const int row = w*32 + qh*16 + m16;
            const int sl = (4*ks + quad) ^ ((row >> 1) & 7);
            af[qh][ks] = *(const short8*)&QsOv[row*128 + sl*8];
        }
    __syncthreads();   // all waves done reading Q; Vt2 free

    // pack V0 -> Vt2[0]
#pragma unroll
    for (int u = 0; u < 2; ++u) {
        const int rp = u*16 + vrp;
#pragma unroll
        for (int i = 0; i < 8; ++i) {
            const int dv = vslot*8 + i;
            const int col = (2*rp) ^ (((dv >> 5) & 3) << 3);
            unsigned int pv = (unsigned int)(unsigned short)va[u][i] |
                              ((unsigned int)(unsigned short)vb[u][i] << 16);
            *(unsigned int*)&Vt2[0][dv*72 + col] = pv;
        }
    }
    __syncthreads();   // Vt2[0] visible; ready for iter 0

    f32x4 O[2][8] = {};
    float mrun[2][4], lrun[2][4];
#pragma unroll
    for (int qh = 0; qh < 2; ++qh)
#pragma unroll
        for (int r = 0; r < 4; ++r) { mrun[qh][r] = -1e30f; lrun[qh][r] = 0.f; }
    unsigned short* Pw = Ps + w*16*72;
    const float SC = 0.08838834764831845f * 1.4426950408889634f; // 1/sqrt(128) * log2(e)

    for (int kt = 0; kt < SEQ/64; ++kt) {
        const int cur = kt & 1;
        const bool pre = (kt + 1 < SEQ/64);
        const long rowkv = rowb + (long)(kt + 1)*64;

        // ---- issue next tile's loads: V -> regs, K -> Ks2[cur^1] async ----
        if (pre) {
#pragma unroll
            for (int u = 0; u < 2; ++u) {
                const int rp = u*16 + vrp;
                va[u] = *(const short8*)(qkv + (rowkv + 2*rp    )*LDQ + vc + vslot*8);
                vb[u] = *(const short8*)(qkv + (rowkv + 2*rp + 1)*LDQ + vc + vslot*8);
            }
#pragma unroll
            for (int u = 0; u < 4; ++u) {
                const int row = u*16 + rbase;
                const int c = slot ^ ((row >> 1) & 7);
                async16(qkv + (rowkv + row)*LDQ + kc + c*8, &Ks2[cur^1][u*2048 + w*512]);
            }
        }

        // ---- S = Q K^T, both q-halves share each K-fragment read ----
        f32x4 S[2][4];
#pragma unroll
        for (int ns = 0; ns < 4; ++ns) {
            f32x4 a0 = {0.f,0.f,0.f,0.f}, a1 = {0.f,0.f,0.f,0.f};
            const int row = ns*16 + m16;
            const int swr = (row >> 1) & 7;
#pragma unroll
            for (int ks = 0; ks < 4; ++ks) {
                const int sl = (4*ks + quad) ^ swr;
                const short8 bfr = *(const short8*)&Ks2[cur][row*128 + sl*8];
                a0 = __builtin_amdgcn_mfma_f32_16x16x32_bf16(af[0][ks], bfr, a0, 0, 0, 0);
                a1 = __builtin_amdgcn_mfma_f32_16x16x32_bf16(af[1][ks], bfr, a1, 0, 0, 0);
            }
#pragma unroll
            for (int r = 0; r < 4; ++r) { a0[r] *= SC; a1[r] *= SC; }
            S[0][ns] = a0; S[1][ns] = a1;
        }

        // ---- per-half: online softmax -> P -> PV (Pw reused; same-wave order) ----
#pragma unroll
        for (int qh = 0; qh < 2; ++qh) {
            float al[4], rs4[4];
#pragma unroll
            for (int r = 0; r < 4; ++r) {
                float tm = fmaxf(fmaxf(S[qh][0][r], S[qh][1][r]), fmaxf(S[qh][2][r], S[qh][3][r]));
                tm = fmaxf(tm, __shfl_xor(tm, 1));
                tm = fmaxf(tm, __shfl_xor(tm, 2));
                tm = fmaxf(tm, __shfl_xor(tm, 4));
                tm = fmaxf(tm, __shfl_xor(tm, 8));
                const float mn = fmaxf(mrun[qh][r], tm);
                al[r] = exp2_fast(mrun[qh][r] - mn);
                mrun[qh][r] = mn;
                rs4[r] = 0.f;
            }
#pragma unroll
            for (int ns = 0; ns < 4; ++ns)
#pragma unroll
                for (int r = 0; r < 4; ++r) {
                    const float p = exp2_fast(S[qh][ns][r] - mrun[qh][r]);
                    rs4[r] += p;
                    Pw[(quad*4 + r)*72 + ns*16 + m16] = f2bf(p);
                }
#pragma unroll
            for (int r = 0; r < 4; ++r) {
                rs4[r] += __shfl_xor(rs4[r], 1);
                rs4[r] += __shfl_xor(rs4[r], 2);
                rs4[r] += __shfl_xor(rs4[r], 4);
                rs4[r] += __shfl_xor(rs4[r], 8);
                lrun[qh][r] = lrun[qh][r]*al[r] + rs4[r];
            }
            // al==1.0 exactly when the running max didn't grow -> skip is exact
            if (__any((al[0] != 1.f) | (al[1] != 1.f) | (al[2] != 1.f) | (al[3] != 1.f))) {
#pragma unroll
                for (int i = 0; i < 8; ++i)
#pragma unroll
                    for (int r = 0; r < 4; ++r) O[qh][i][r] *= al[r];
            }

            // pack next V tile late (after most compute, before final PV)
            if (qh == 1 && pre) {
#pragma unroll
                for (int u = 0; u < 2; ++u) {
                    const int rp = u*16 + vrp;
#pragma unroll
                    for (int i = 0; i < 8; ++i) {
                        const int dv = vslot*8 + i;
                        const int col = (2*rp) ^ (((dv >> 5) & 3) << 3);
                        unsigned int pv = (unsigned int)(unsigned short)va[u][i] |
                                          ((unsigned int)(unsigned short)vb[u][i] << 16);
                        *(unsigned int*)&Vt2[cur^1][dv*72 + col] = pv;
                    }
                }
            }

            // O[qh] += P V
#pragma unroll
            for (int ks2 = 0; ks2 < 2; ++ks2) {
                const short8 ap = *(const short8*)&Pw[m16*72 + ks2*32 + quad*8];
#pragma unroll
                for (int ds = 0; ds < 8; ++ds) {
                    const int dv = ds*16 + m16;
                    const int jcol = (ks2*32 + quad*8) ^ (((dv >> 5) & 3) << 3);
                    const short8 bv = *(const short8*)&Vt2[cur][dv*72 + jcol];
                    O[qh][ds] = __builtin_amdgcn_mfma_f32_16x16x32_bf16(ap, bv, O[qh][ds], 0, 0, 0);
                }
            }
        }

        // single barrier: drains K glds (Ks2[cur^1] ready), publishes Vt2[cur^1],
        // fences all reads of Ks2[cur]/Vt2[cur] before iter kt+1 overwrites them.
        __syncthreads();
    }

    // ---- normalize + write O over the Q columns ----
    float inv[2][4];
#pragma unroll
    for (int qh = 0; qh < 2; ++qh)
#pragma unroll
        for (int r = 0; r < 4; ++r) inv[qh][r] = 1.0f / lrun[qh][r];
#pragma unroll
    for (int qh = 0; qh < 2; ++qh)
#pragma unroll
        for (int ds = 0; ds < 8; ++ds)
#pragma unroll
            for (int r = 0; r < 4; ++r) {
                const long row = rowq + w*32 + qh*16 + quad*4 + r;
                qkv[row*LDQ + qc + ds*16 + m16] = f2bf(O[qh][ds][r] * inv[qh][r]);
            }
}

// ---------------------------------------------------------------------------
// LayerNorm over bf16 rows. OUTF32=1 writes fp32 (final output), else bf16.
// ---------------------------------------------------------------------------
template<int OUTF32>
__global__ __launch_bounds__(256)
void ln_bf16(const unsigned short* __restrict__ X, const float* __restrict__ g,
             const float* __restrict__ be, void* __restrict__ Y)
{
    __shared__ float r1[256], r2[256];
    const int t = threadIdx.x;
    const long row = blockIdx.x;
    const unsigned short* x = X + row*EMBED;
    float v[8];
    const short8 xv = *(const short8*)(x + t*8);
    float s = 0.f, s2 = 0.f;
#pragma unroll
    for (int i = 0; i < 8; ++i) {
        v[i] = bf2f((unsigned short)xv[i]);
        s += v[i]; s2 += v[i]*v[i];
    }
    r1[t] = s; r2[t] = s2;
    __syncthreads();
    for (int k = 128; k > 0; k >>= 1) {
        if (t < k) { r1[t] += r1[t+k]; r2[t] += r2[t+k]; }
        __syncthreads();
    }
    const float mu = r1[0] * (1.0f/EMBED);
    const float var = r2[0] * (1.0f/EMBED) - mu*mu;
    const float rstd = rsqrtf(var + 1e-5f);
    if (OUTF32) {
        float* y = (float*)Y + row*EMBED + t*8;
#pragma unroll
        for (int i = 0; i < 8; ++i) y[i] = (v[i]-mu)*rstd*g[t*8+i] + be[t*8+i];
    } else {
        unsigned short* y = (unsigned short*)Y + row*EMBED;
        short8 o;
#pragma unroll
        for (int i = 0; i < 8; ++i) o[i] = (short)f2bf((v[i]-mu)*rstd*g[t*8+i] + be[t*8+i]);
        *(short8*)(y + t*8) = o;
    }
}

// ---------------------------------------------------------------------------
// fp32 W[K][N] -> bf16 Wt[N][K] (transpose + convert), 32x32 LDS tiles
// ---------------------------------------------------------------------------
__global__ __launch_bounds__(256)
void cvt_transpose(const float* __restrict__ W, unsigned short* __restrict__ Wt, int K, int N)
{
    __shared__ unsigned short T[32][33];
    const int t = threadIdx.x;
    const long n0 = (long)blockIdx.x*32, k0 = (long)blockIdx.y*32;
    {
        const int r = t >> 3, c = (t & 7)*4;
        const float4 vv = *(const float4*)&W[(k0 + r)*N + n0 + c];
        T[r][c+0] = f2bf(vv.x); T[r][c+1] = f2bf(vv.y);
        T[r][c+2] = f2bf(vv.z); T[r][c+3] = f2bf(vv.w);
    }
    __syncthreads();
    const int rn = t >> 3, kk = (t & 7)*4;
    unsigned int p0 = (unsigned int)T[kk+0][rn] | ((unsigned int)T[kk+1][rn] << 16);
    unsigned int p1 = (unsigned int)T[kk+2][rn] | ((unsigned int)T[kk+3][rn] << 16);
    unsigned int* dst = (unsigned int*)&Wt[(n0 + rn)*K + k0 + kk];
    dst[0] = p0; dst[1] = p1;
}

__global__ __launch_bounds__(256)
void cvt_f32_bf16(const float* __restrict__ X, unsigned short* __restrict__ Y, long n)
{
    const long i = ((long)blockIdx.x*256 + threadIdx.x)*8;
    if (i >= n) return;
    const float4 a = *(const float4*)&X[i];
    const float4 b = *(const float4*)&X[i+4];
    short8 o;
    o[0]=(short)f2bf(a.x); o[1]=(short)f2bf(a.y); o[2]=(short)f2bf(a.z); o[3]=(short)f2bf(a.w);
    o[4]=(short)f2bf(b.x); o[5]=(short)f2bf(b.y); o[6]=(short)f2bf(b.z); o[7]=(short)f2bf(b.w);
    *(short8*)&Y[i] = o;
}

__global__ __launch_bounds__(256)
void concat_bias(const float* __restrict__ bq, const float* __restrict__ bk,
                 const float* __restrict__ bv, float* __restrict__ out)
{
    const int i = blockIdx.x*256 + threadIdx.x;
    if (i < 2048) out[i] = bq[i];
    else if (i < 4096) out[i] = bk[i-2048];
    else if (i < 6144) out[i] = bv[i-4096];
}

// ---------------------------------------------------------------------------
extern "C" void kernel_launch(void* const* d_in, const int* in_sizes, int n_in,
                              void* d_out, int out_size, void* d_ws, size_t ws_size,
                              hipStream_t stream)
{
    const float* x   = (const float*)d_in[0];
    const float* Wq  = (const float*)d_in[1];
    const float* bq  = (const float*)d_in[2];
    const float* Wk  = (const float*)d_in[3];
    const float* bk  = (const float*)d_in[4];
    const float* Wv  = (const float*)d_in[5];
    const float* bv  = (const float*)d_in[6];
    const float* Wo  = (const float*)d_in[7];
    const float* bo  = (const float*)d_in[8];
    const float* g1  = (const float*)d_in[9];
    const float* b1  = (const float*)d_in[10];
    const float* g2v = (const float*)d_in[11];
    const float* b2v = (const float*)d_in[12];
    const float* W1  = (const float*)d_in[13];
    const float* bf1 = (const float*)d_in[14];
    const float* W2  = (const float*)d_in[15];
    const float* bf2 = (const float*)d_in[16];
    float* out = (float*)d_out;

    // ---- workspace arena (byte offsets; total 184,573,952 B < 192 MiB) ----
    char* ws = (char*)d_ws;
    unsigned short* Wqkvt = (unsigned short*)(ws + 0);          // 25.2 MB [dead after GEMM1]
    unsigned short* Wot   = (unsigned short*)(ws + 25165824);   //  8.4 MB
    unsigned short* W1t   = (unsigned short*)(ws + 33554432);   // 33.6 MB
    unsigned short* W2t   = (unsigned short*)(ws + 67108864);   // 33.6 MB
    float*          bqkv  = (float*)         (ws + 100663296);  // 24 KB
    char* arenaA = ws + 100687872;                              // 67.1 MB arena
    unsigned short* xb   = (unsigned short*)(arenaA);           // 16.8 MB [cvt_x, GEMM1]
    unsigned short* qkv  = (unsigned short*)(arenaA + 16777216);// 50.3 MB [GEMM1, GEMM2]
    unsigned short* res1 = (unsigned short*)(arenaA);           // reuse xb slot [GEMM2, LN1]
    unsigned short* ff   = (unsigned short*)(arenaA);           // full arena [GEMM3, GEMM4]
    unsigned short* hb   = (unsigned short*)(ws + 167796736);   // 16.8 MB [LN1, GEMM4]
    unsigned short* res2 = (unsigned short*)(ws + 0);           // reuse Wqkvt slot [GEMM4, LN2]

    const dim3 blk(256);

    // weights: fp32 -> bf16 transposed
    cvt_transpose<<<dim3(64,64),  blk, 0, stream>>>(Wq, Wqkvt,             2048, 2048);
    cvt_transpose<<<dim3(64,64),  blk, 0, stream>>>(Wk, Wqkvt + 2048*2048, 2048, 2048);
    cvt_transpose<<<dim3(64,64),  blk, 0, stream>>>(Wv, Wqkvt + 2*2048*2048, 2048, 2048);
    cvt_transpose<<<dim3(64,64),  blk, 0, stream>>>(Wo, Wot, 2048, 2048);
    cvt_transpose<<<dim3(256,64), blk, 0, stream>>>(W1, W1t, 2048, 8192);
    cvt_transpose<<<dim3(64,256), blk, 0, stream>>>(W2, W2t, 8192, 2048);
    concat_bias<<<dim3(24), blk, 0, stream>>>(bq, bk, bv, bqkv);
    cvt_f32_bf16<<<dim3(4096), blk, 0, stream>>>(x, xb, (long)TOK*EMBED);

    // fused QKV projection -> qkv[4096][6144]
    gemm_bf16<0><<<dim3(48,32), blk, 0, stream>>>(xb, Wqkvt, bqkv, nullptr, qkv, TOK, 6144, 2048, 2048);
    // flash attention (O overwrites q-columns in-place); 512 blocks (QBLK=128)
    attn_flash<<<dim3(512), blk, 0, stream>>>(qkv);
    // output projection + residual(x, fp32)
    gemm_bf16<1><<<dim3(16,32), blk, 0, stream>>>(qkv, Wot, bo, x, res1, TOK, 2048, 2048, 6144);
    ln_bf16<0><<<dim3(4096), blk, 0, stream>>>(res1, g1, b1, hb);
    // FFN
    gemm_bf16<2><<<dim3(64,32), blk, 0, stream>>>(hb, W1t, bf1, nullptr, ff, TOK, 8192, 2048, 2048);
    gemm_bf16<3><<<dim3(16,32), blk, 0, stream>>>(ff, W2t, bf2, hb, res2, TOK, 2048, 8192, 8192);
    ln_bf16<1><<<dim3(4096), blk, 0, stream>>>(res2, g2v, b2v, out);
}

// Round 7
// 912.705 us; speedup vs baseline: 1.1125x; 1.0188x over previous
//
#include <hip/hip_runtime.h>
#include <math.h>

#define EMBED 2048
#define DFF   8192
#define TOK   4096
#define SEQ   2048
#define HEADS 16
#define HD    128
#define LDQ   6144   // qkv row stride in elements (q|k|v concatenated)

typedef __attribute__((ext_vector_type(8))) short short8;
typedef __attribute__((ext_vector_type(4))) float f32x4;

__device__ __forceinline__ unsigned short f2bf(float f) {
    unsigned int u = __float_as_uint(f);
    return (unsigned short)((u + 0x7FFFu + ((u >> 16) & 1u)) >> 16);  // RNE
}
__device__ __forceinline__ float bf2f(unsigned short s) {
    return __uint_as_float(((unsigned int)s) << 16);
}
// 2^x via v_exp_f32 (native base-2). NOTE: name must not be __exp2f — glibc
// math.h declares that symbol and the collision breaks gfx950 compilation.
__device__ __forceinline__ float exp2_fast(float x) {
    return __builtin_amdgcn_exp2f(x);
}

// async global->LDS, 16B per lane. LDS dest = wave-uniform base + lane*16.
__device__ __forceinline__ void async16(const void* g, void* l) {
    __builtin_amdgcn_global_load_lds((const __attribute__((address_space(1))) void*)g,
                                     (__attribute__((address_space(3))) void*)l, 16, 0, 0);
}

// fast GELU (tanh form): v * sigmoid(1.5957691*(v + 0.044715 v^3)); |err|<~1e-3
__device__ __forceinline__ float gelu_fast(float v) {
    const float y = 1.5957691216057308f * (v + 0.044715f * v * v * v);
    return v / (1.0f + __expf(-y));
}

// ---------------------------------------------------------------------------
// R10/R11: 8-wave counted-vmcnt GEMM (T3+T4+T2+T5 port, plain HIP).
// C[M,N](bf16) = A[M,K](bf16) @ Wt[N,K](bf16)^T + bias (+epilogue).
// 512 thr = 8 waves (2M x 4N). Tile BM x 256, BK=64 as two 32-K slices.
// Pipeline invariant: stage order per K-tile is [slice0][slice1], each
// LA+2 loads/thread (A:LA, B:2). Phase kk: wait vmcnt(LA+2) -> exactly the
// newest slice-set may be in flight, everything older (this phase's data)
// has landed; raw s_barrier; issue next tile's slice kk; ds_read (swizzled,
// conflict-free) -> MFMA (setprio-wrapped). Never vmcnt(0) in-loop (T4);
// the wait at the last iteration's phase 1 is the only full drain.
// LDS swizzle: LDS[r][s] = G[r][s ^ ((r>>1)&3)] via pre-swizzled global
// source (gload_lds dest stays linear); reads XOR the same -> 2-way max.
// MODE: 0 plain, 2 +GELU, 3 +resid bf16. Output bf16.
// ---------------------------------------------------------------------------
template<int BM, int MODE>
__global__ __launch_bounds__(512, 2)
void gemm8p(const unsigned short* __restrict__ A, const unsigned short* __restrict__ B,
            const float* __restrict__ bias, const void* __restrict__ resid,
            unsigned short* __restrict__ C, int M, int N, int K, int lda)
{
    constexpr int ASLICE = BM * 32;       // shorts per A K-slice
    constexpr int BSLICE = 256 * 32;      // shorts per B K-slice
    constexpr int LA = BM / 128;          // A loads/thread/slice (2 or 1)
    constexpr int MF = BM / 32;           // m-frags per wave (8 or 4)
    __shared__ __align__(16) unsigned short sm[4*ASLICE + 4*BSLICE];

    const int t = threadIdx.x;
    const int w = t >> 6, l = t & 63;
    const int quad = l >> 4, m16 = l & 15;
    const int wm = w >> 2, wn = w & 3;
    const long bm = (long)blockIdx.y * BM, bn = (long)blockIdx.x * 256;

    f32x4 acc[MF][4] = {};

    const unsigned short* Ag = A + (size_t)bm*lda;
    const unsigned short* Bg = B + (size_t)bn*K;

    // staging lambdas: element e = p*512 + t ; r = e>>2 ; s = e&3
    auto stageA = [&](int buf, int ks, int k0) {
#pragma unroll
        for (int p = 0; p < LA; ++p) {
            const int e = p*512 + t;
            const int r = e >> 2, s = e & 3;
            const int gc = k0 + ks*32 + (s ^ ((r >> 1) & 3))*8;
            async16(Ag + (size_t)r*lda + gc,
                    sm + buf*2*ASLICE + ks*ASLICE + (p*512 + w*64)*8);
        }
    };
    auto stageB = [&](int buf, int ks, int k0) {
#pragma unroll
        for (int p = 0; p < 2; ++p) {
            const int e = p*512 + t;
            const int r = e >> 2, s = e & 3;
            const int gc = k0 + ks*32 + (s ^ ((r >> 1) & 3))*8;
            async16(Bg + (size_t)r*K + gc,
                    sm + 4*ASLICE + buf*2*BSLICE + ks*BSLICE + (p*512 + w*64)*8);
        }
    };

    // prologue: tile 0, both slices
    stageA(0, 0, 0); stageB(0, 0, 0);
    stageA(0, 1, 0); stageB(0, 1, 0);

    const int iters = K >> 6;
    for (int it = 0; it < iters; ++it) {
        const int cur = it & 1;
        const bool pre = (it + 1 < iters);
        const int kn = (it + 1) << 6;

#pragma unroll
        for (int kk = 0; kk < 2; ++kk) {
            // wait: everything older than the newest slice-set has landed
            if (kk == 0 || pre) {
                if constexpr (BM == 256) asm volatile("s_waitcnt vmcnt(4)" ::: "memory");
                else                     asm volatile("s_waitcnt vmcnt(3)" ::: "memory");
            } else {
                asm volatile("s_waitcnt vmcnt(0)" ::: "memory");
            }
            __builtin_amdgcn_s_barrier();
            if (pre) { stageA(cur ^ 1, kk, kn); stageB(cur ^ 1, kk, kn); }

            const unsigned short* Ab = sm + cur*2*ASLICE + kk*ASLICE;
            const unsigned short* Bb = sm + 4*ASLICE + cur*2*BSLICE + kk*BSLICE;
            short8 afr[MF], bfr[4];
#pragma unroll
            for (int m = 0; m < MF; ++m) {
                const int R = wm*(BM/2) + m*16 + m16;
                const int sl = quad ^ ((R >> 1) & 3);
                afr[m] = *(const short8*)(Ab + R*32 + sl*8);
            }
#pragma unroll
            for (int n = 0; n < 4; ++n) {
                const int R = wn*64 + n*16 + m16;
                const int sl = quad ^ ((R >> 1) & 3);
                bfr[n] = *(const short8*)(Bb + R*32 + sl*8);
            }
            __builtin_amdgcn_s_setprio(1);
#pragma unroll
            for (int m = 0; m < MF; ++m)
#pragma unroll
                for (int n = 0; n < 4; ++n)
                    acc[m][n] = __builtin_amdgcn_mfma_f32_16x16x32_bf16(afr[m], bfr[n], acc[m][n], 0, 0, 0);
            __builtin_amdgcn_s_setprio(0);
        }
    }

    // ---- epilogue: acc -> LDS (f32) -> coalesced bf16 stores, 64-row passes ----
    __syncthreads();               // full drain; K-loop LDS dead
    asm volatile("" ::: "memory");
    float* Cs = (float*)sm;        // Cs[64][260] f32 = 66,560 B (fits both BM)
    const int ecol = (t & 31) * 8;
    float bias8[8];
#pragma unroll
    for (int i = 0; i < 8; ++i) bias8[i] = bias[bn + ecol + i];

    constexpr int NP = BM / 64;
#pragma unroll
    for (int p = 0; p < NP; ++p) {
        if (p) __syncthreads();
        constexpr int HW = (NP == 4) ? 2 : 1;   // passes per wm
        const int pwm = p / HW;
        const int mp = (NP == 4) ? (p & 1)*4 : 0;
        if (wm == pwm) {
#pragma unroll
            for (int mi = 0; mi < 4; ++mi)
#pragma unroll
                for (int n = 0; n < 4; ++n)
#pragma unroll
                    for (int r = 0; r < 4; ++r)
                        Cs[(mi*16 + quad*4 + r)*260 + wn*64 + n*16 + m16] = acc[mp + mi][n][r];
        }
        __syncthreads();
#pragma unroll
        for (int j = 0; j < 4; ++j) {
            const int row = j*16 + (t >> 5);
            float v[8];
            *(f32x4*)&v[0] = *(const f32x4*)&Cs[row*260 + ecol];
            *(f32x4*)&v[4] = *(const f32x4*)&Cs[row*260 + ecol + 4];
            const long gr = bm + p*64 + row;
            const long go = gr*N + bn + ecol;
            short8 rb16;
            if (MODE == 3) rb16 = *(const short8*)((const unsigned short*)resid + go);
            short8 o;
#pragma unroll
            for (int i = 0; i < 8; ++i) {
                float y = v[i] + bias8[i];
                if (MODE == 3) y += bf2f((unsigned short)rb16[i]);
                if (MODE == 2) y = gelu_fast(y);
                o[i] = (short)f2bf(y);
            }
            *(short8*)&C[go] = o;
        }
    }
}

// ---------------------------------------------------------------------------
// Old 128x128 2-barrier GEMM — kept for the small attn-projection GEMM
// (N=2048 at 512 grid of 256-thr blocks keeps the whole GPU busy; a 512-thr
// 256-tile grid there would be only 128 blocks = half the CUs idle).
// MODE: 0 plain, 1 +resid f32, 2 +GELU, 3 +resid bf16. Output always bf16.
// ---------------------------------------------------------------------------
template<int MODE>
__global__ __launch_bounds__(256, 2)
void gemm_bf16(const unsigned short* __restrict__ A, const unsigned short* __restrict__ B,
               const float* __restrict__ bias, const void* __restrict__ resid,
               unsigned short* __restrict__ C, int M, int N, int K, int lda)
{
    __shared__ __align__(16) float smemf[8448];          // 33.8 KB, multi-use
    unsigned short* As = (unsigned short*)smemf;         // As[2][4096] u16
    unsigned short* Bs = As + 8192;                      // Bs[2][4096] u16
    float* Cs = smemf;                                   // Cs[64][132] f32 (epilogue)

    const int t = threadIdx.x;
    const int w = t >> 6, l = t & 63;
    const int quad = l >> 4, m16 = l & 15;
    const long bm = (long)blockIdx.y * 128, bn = (long)blockIdx.x * 128;
    const int wr = (w >> 1)*64, wc = (w & 1)*64;   // this wave's 64x64 quadrant

    f32x4 acc[4][4] = {};

    const int srow = w*16 + (l >> 2);   // staging row (+u*64)
    const int sslot = l & 3;
    const unsigned short* Ag = A + (size_t)bm*lda;
    const unsigned short* Bg = B + (size_t)bn*K;

    // prologue: stage tile 0 -> buffer 0
#pragma unroll
    for (int u = 0; u < 2; ++u) {
        const int row = u*64 + srow;
        const int c = sslot ^ ((row >> 1) & 3);
        async16(Ag + (size_t)row*lda + c*8, &As[u*2048 + w*512]);
        async16(Bg + (size_t)row*K   + c*8, &Bs[u*2048 + w*512]);
    }

    const int iters = K >> 5;
    for (int it = 0; it < iters; ++it) {
        __syncthreads();   // drains tile-it glds (in flight since last iter)
        if (it + 1 < iters) {
            const int k0 = (it + 1) << 5;
            const int bo = ((it + 1) & 1) * 4096;
#pragma unroll
            for (int u = 0; u < 2; ++u) {
                const int row = u*64 + srow;
                const int c = sslot ^ ((row >> 1) & 3);
                async16(Ag + (size_t)row*lda + k0 + c*8, &As[bo + u*2048 + w*512]);
                async16(Bg + (size_t)row*K   + k0 + c*8, &Bs[bo + u*2048 + w*512]);
            }
        }
        const int co = (it & 1) * 4096;
        short8 af[4], bf[4];
#pragma unroll
        for (int s = 0; s < 4; ++s) {
            const int ra = wr + s*16 + m16;
            const int sla = quad ^ ((ra >> 1) & 3);
            af[s] = *(const short8*)&As[co + ra*32 + sla*8];
            const int rb = wc + s*16 + m16;
            const int slb = quad ^ ((rb >> 1) & 3);
            bf[s] = *(const short8*)&Bs[co + rb*32 + slb*8];
        }
#pragma unroll
        for (int ms = 0; ms < 4; ++ms)
#pragma unroll
            for (int ns = 0; ns < 4; ++ns)
                acc[ms][ns] = __builtin_amdgcn_mfma_f32_16x16x32_bf16(af[ms], bf[ns], acc[ms][ns], 0, 0, 0);
    }

    // ---- epilogue via LDS: 2 passes of 64 rows ----
    const int ecol = (t & 15) * 8;          // this lane's 8 output cols
    float bias8[8];
#pragma unroll
    for (int i = 0; i < 8; ++i) bias8[i] = bias[bn + ecol + i];

#pragma unroll
    for (int pass = 0; pass < 2; ++pass) {
        __syncthreads();   // prior LDS use (K-loop buffers / previous pass) done
        if ((w >> 1) == pass) {   // waves owning rows [pass*64, pass*64+64) stage
#pragma unroll
            for (int ms = 0; ms < 4; ++ms)
#pragma unroll
                for (int ns = 0; ns < 4; ++ns)
#pragma unroll
                    for (int r = 0; r < 4; ++r)
                        Cs[(ms*16 + quad*4 + r)*132 + wc + ns*16 + m16] = acc[ms][ns][r];
        }
        __syncthreads();
#pragma unroll
        for (int j = 0; j < 4; ++j) {
            const int row = j*16 + (t >> 4);
            float v[8];
            *(f32x4*)&v[0] = *(const f32x4*)&Cs[row*132 + ecol];
            *(f32x4*)&v[4] = *(const f32x4*)&Cs[row*132 + ecol + 4];
            const long gr = bm + pass*64 + row;
            const long go = gr*N + bn + ecol;
            float r8[8];
            if (MODE == 1) {
                *(f32x4*)&r8[0] = *(const f32x4*)((const float*)resid + go);
                *(f32x4*)&r8[4] = *(const f32x4*)((const float*)resid + go + 4);
            }
            short8 rb16;
            if (MODE == 3) rb16 = *(const short8*)((const unsigned short*)resid + go);
            short8 o;
#pragma unroll
            for (int i = 0; i < 8; ++i) {
                float y = v[i] + bias8[i];
                if (MODE == 1) y += r8[i];
                if (MODE == 3) y += bf2f((unsigned short)rb16[i]);
                if (MODE == 2) y = gelu_fast(y);
                o[i] = (short)f2bf(y);
            }
            *(short8*)&C[go] = o;
        }
    }
}

// ---------------------------------------------------------------------------
// Flash attention, bf16 MFMA. One block = (b, h, 128-row Q tile). 256 thr.
// (R9 structure: QBLK=128 dual-accumulate, XCD-chunked swizzle, single
// barrier/iter, base-2 softmax, exact rescale-skip. Unchanged.)
// ---------------------------------------------------------------------------
__global__ __launch_bounds__(256, 2)
void attn_flash(unsigned short* __restrict__ qkv)
{
    __shared__ unsigned short Ks2[2][64*128]; // K dbuf (32,768 B)
    __shared__ unsigned short Vt2[2][128*72]; // V^T dbuf [d][j] (36,864 B); Q-staging overlay
    __shared__ unsigned short Ps[4*16*72];    // per-wave P scratch (9,216 B)

    const int t = threadIdx.x;
    const int w = t >> 6, l = t & 63;
    const int quad = l >> 4, m16 = l & 15;

    // XCD-chunked decode: 512 dispatches, XCD = d&7, 64 blocks/XCD = 4 bh's
    const int dd = blockIdx.x;
    const int bh = (dd & 7)*4 + ((dd >> 3) >> 4);  // 0..31
    const int qt = (dd >> 3) & 15;                 // 0..15 (128-row tiles)
    const int b = bh >> 4, h = bh & 15;

    const long rowq = (long)b*SEQ + qt*128;
    const long rowb = (long)b*SEQ;
    const int qc = h*HD;
    const int kc = EMBED + h*HD;
    const int vc = 2*EMBED + h*HD;

    const int rbase = w*4 + (l >> 4);   // K/Q staging row base
    const int slot  = l & 15;           // K/Q staging 16B slot
    const int vslot = t & 15;           // V staging d-slot
    const int vrp   = t >> 4;           // V staging row-pair base

    unsigned short* QsOv = (unsigned short*)Vt2;   // Q overlay: 128*128*2 = 32 KB <= 36,864 B

    // ---- prologue: V0 -> regs (oldest vmcnt entries), Q -> QsOv, K0 -> Ks2[0] ----
    short8 va[2], vb[2];
#pragma unroll
    for (int u = 0; u < 2; ++u) {
        const int rp = u*16 + vrp;
        va[u] = *(const short8*)(qkv + (rowb + 2*rp    )*LDQ + vc + vslot*8);
        vb[u] = *(const short8*)(qkv + (rowb + 2*rp + 1)*LDQ + vc + vslot*8);
    }
#pragma unroll
    for (int u = 0; u < 8; ++u) {   // Q: 128 rows
        const int row = u*16 + rbase;
        const int c = slot ^ ((row >> 1) & 7);
        async16(qkv + (rowq + row)*LDQ + qc + c*8, QsOv + u*2048 + w*512);
    }
#pragma unroll
    for (int u = 0; u < 4; ++u) {   // K0: 64 rows
        const int row = u*16 + rbase;
        const int c = slot ^ ((row >> 1) & 7);
        async16(qkv + (rowb + row)*LDQ + kc + c*8, &Ks2[0][u*2048 + w*512]);
    }
    __syncthreads();   // Q + K0 staged

    // Q A-frags: wave w owns q-rows [w*32, w*32+32), two 16-row halves
    short8 af[2][4];
#pragma unroll
    for (int qh = 0; qh < 2; ++qh)
#pragma unroll
        for (int ks = 0; ks < 4; ++ks) {
            const int row = w*32 + qh*16 + m16;
            const int sl = (4*ks + quad) ^ ((row >> 1) & 7);
            af[qh][ks] = *(const short8*)&QsOv[row*128 + sl*8];
        }
    __syncthreads();   // all waves done reading Q; Vt2 free

    // pack V0 -> Vt2[0]
#pragma unroll
    for (int u = 0; u < 2; ++u) {
        const int rp = u*16 + vrp;
#pragma unroll
        for (int i = 0; i < 8; ++i) {
            const int dv = vslot*8 + i;
            const int col = (2*rp) ^ (((dv >> 5) & 3) << 3);
            unsigned int pv = (unsigned int)(unsigned short)va[u][i] |
                              ((unsigned int)(unsigned short)vb[u][i] << 16);
            *(unsigned int*)&Vt2[0][dv*72 + col] = pv;
        }
    }
    __syncthreads();   // Vt2[0] visible; ready for iter 0

    f32x4 O[2][8] = {};
    float mrun[2][4], lrun[2][4];
#pragma unroll
    for (int qh = 0; qh < 2; ++qh)
#pragma unroll
        for (int r = 0; r < 4; ++r) { mrun[qh][r] = -1e30f; lrun[qh][r] = 0.f; }
    unsigned short* Pw = Ps + w*16*72;
    const float SC = 0.08838834764831845f * 1.4426950408889634f; // 1/sqrt(128) * log2(e)

    for (int kt = 0; kt < SEQ/64; ++kt) {
        const int cur = kt & 1;
        const bool pre = (kt + 1 < SEQ/64);
        const long rowkv = rowb + (long)(kt + 1)*64;

        // ---- issue next tile's loads: V -> regs, K -> Ks2[cur^1] async ----
        if (pre) {
#pragma unroll
            for (int u = 0; u < 2; ++u) {
                const int rp = u*16 + vrp;
                va[u] = *(const short8*)(qkv + (rowkv + 2*rp    )*LDQ + vc + vslot*8);
                vb[u] = *(const short8*)(qkv + (rowkv + 2*rp + 1)*LDQ + vc + vslot*8);
            }
#pragma unroll
            for (int u = 0; u < 4; ++u) {
                const int row = u*16 + rbase;
                const int c = slot ^ ((row >> 1) & 7);
                async16(qkv + (rowkv + row)*LDQ + kc + c*8, &Ks2[cur^1][u*2048 + w*512]);
            }
        }

        // ---- S = Q K^T, both q-halves share each K-fragment read ----
        f32x4 S[2][4];
#pragma unroll
        for (int ns = 0; ns < 4; ++ns) {
            f32x4 a0 = {0.f,0.f,0.f,0.f}, a1 = {0.f,0.f,0.f,0.f};
            const int row = ns*16 + m16;
            const int swr = (row >> 1) & 7;
#pragma unroll
            for (int ks = 0; ks < 4; ++ks) {
                const int sl = (4*ks + quad) ^ swr;
                const short8 bfr = *(const short8*)&Ks2[cur][row*128 + sl*8];
                a0 = __builtin_amdgcn_mfma_f32_16x16x32_bf16(af[0][ks], bfr, a0, 0, 0, 0);
                a1 = __builtin_amdgcn_mfma_f32_16x16x32_bf16(af[1][ks], bfr, a1, 0, 0, 0);
            }
#pragma unroll
            for (int r = 0; r < 4; ++r) { a0[r] *= SC; a1[r] *= SC; }
            S[0][ns] = a0; S[1][ns] = a1;
        }

        // ---- per-half: online softmax -> P -> PV (Pw reused; same-wave order) ----
#pragma unroll
        for (int qh = 0; qh < 2; ++qh) {
            float al[4], rs4[4];
#pragma unroll
            for (int r = 0; r < 4; ++r) {
                float tm = fmaxf(fmaxf(S[qh][0][r], S[qh][1][r]), fmaxf(S[qh][2][r], S[qh][3][r]));
                tm = fmaxf(tm, __shfl_xor(tm, 1));
                tm = fmaxf(tm, __shfl_xor(tm, 2));
                tm = fmaxf(tm, __shfl_xor(tm, 4));
                tm = fmaxf(tm, __shfl_xor(tm, 8));
                const float mn = fmaxf(mrun[qh][r], tm);
                al[r] = exp2_fast(mrun[qh][r] - mn);
                mrun[qh][r] = mn;
                rs4[r] = 0.f;
            }
#pragma unroll
            for (int ns = 0; ns < 4; ++ns)
#pragma unroll
                for (int r = 0; r < 4; ++r) {
                    const float p = exp2_fast(S[qh][ns][r] - mrun[qh][r]);
                    rs4[r] += p;
                    Pw[(quad*4 + r)*72 + ns*16 + m16] = f2bf(p);
                }
#pragma unroll
            for (int r = 0; r < 4; ++r) {
                rs4[r] += __shfl_xor(rs4[r], 1);
                rs4[r] += __shfl_xor(rs4[r], 2);
                rs4[r] += __shfl_xor(rs4[r], 4);
                rs4[r] += __shfl_xor(rs4[r], 8);
                lrun[qh][r] = lrun[qh][r]*al[r] + rs4[r];
            }
            // al==1.0 exactly when the running max didn't grow -> skip is exact
            if (__any((al[0] != 1.f) | (al[1] != 1.f) | (al[2] != 1.f) | (al[3] != 1.f))) {
#pragma unroll
                for (int i = 0; i < 8; ++i)
#pragma unroll
                    for (int r = 0; r < 4; ++r) O[qh][i][r] *= al[r];
            }

            // pack next V tile late (after most compute, before final PV)
            if (qh == 1 && pre) {
#pragma unroll
                for (int u = 0; u < 2; ++u) {
                    const int rp = u*16 + vrp;
#pragma unroll
                    for (int i = 0; i < 8; ++i) {
                        const int dv = vslot*8 + i;
                        const int col = (2*rp) ^ (((dv >> 5) & 3) << 3);
                        unsigned int pv = (unsigned int)(unsigned short)va[u][i] |
                                          ((unsigned int)(unsigned short)vb[u][i] << 16);
                        *(unsigned int*)&Vt2[cur^1][dv*72 + col] = pv;
                    }
                }
            }

            // O[qh] += P V
#pragma unroll
            for (int ks2 = 0; ks2 < 2; ++ks2) {
                const short8 ap = *(const short8*)&Pw[m16*72 + ks2*32 + quad*8];
#pragma unroll
                for (int ds = 0; ds < 8; ++ds) {
                    const int dv = ds*16 + m16;
                    const int jcol = (ks2*32 + quad*8) ^ (((dv >> 5) & 3) << 3);
                    const short8 bv = *(const short8*)&Vt2[cur][dv*72 + jcol];
                    O[qh][ds] = __builtin_amdgcn_mfma_f32_16x16x32_bf16(ap, bv, O[qh][ds], 0, 0, 0);
                }
            }
        }

        // single barrier: drains K glds (Ks2[cur^1] ready), publishes Vt2[cur^1],
        // fences all reads of Ks2[cur]/Vt2[cur] before iter kt+1 overwrites them.
        __syncthreads();
    }

    // ---- normalize + write O over the Q columns ----
    float inv[2][4];
#pragma unroll
    for (int qh = 0; qh < 2; ++qh)
#pragma unroll
        for (int r = 0; r < 4; ++r) inv[qh][r] = 1.0f / lrun[qh][r];
#pragma unroll
    for (int qh = 0; qh < 2; ++qh)
#pragma unroll
        for (int ds = 0; ds < 8; ++ds)
#pragma unroll
            for (int r = 0; r < 4; ++r) {
                const long row = rowq + w*32 + qh*16 + quad*4 + r;
                qkv[row*LDQ + qc + ds*16 + m16] = f2bf(O[qh][ds][r] * inv[qh][r]);
            }
}

// ---------------------------------------------------------------------------
// LayerNorm over bf16 rows. OUTF32=1 writes fp32 (final output), else bf16.
// ---------------------------------------------------------------------------
template<int OUTF32>
__global__ __launch_bounds__(256)
void ln_bf16(const unsigned short* __restrict__ X, const float* __restrict__ g,
             const float* __restrict__ be, void* __restrict__ Y)
{
    __shared__ float r1[256], r2[256];
    const int t = threadIdx.x;
    const long row = blockIdx.x;
    const unsigned short* x = X + row*EMBED;
    float v[8];
    const short8 xv = *(const short8*)(x + t*8);
    float s = 0.f, s2 = 0.f;
#pragma unroll
    for (int i = 0; i < 8; ++i) {
        v[i] = bf2f((unsigned short)xv[i]);
        s += v[i]; s2 += v[i]*v[i];
    }
    r1[t] = s; r2[t] = s2;
    __syncthreads();
    for (int k = 128; k > 0; k >>= 1) {
        if (t < k) { r1[t] += r1[t+k]; r2[t] += r2[t+k]; }
        __syncthreads();
    }
    const float mu = r1[0] * (1.0f/EMBED);
    const float var = r2[0] * (1.0f/EMBED) - mu*mu;
    const float rstd = rsqrtf(var + 1e-5f);
    if (OUTF32) {
        float* y = (float*)Y + row*EMBED + t*8;
#pragma unroll
        for (int i = 0; i < 8; ++i) y[i] = (v[i]-mu)*rstd*g[t*8+i] + be[t*8+i];
    } else {
        unsigned short* y = (unsigned short*)Y + row*EMBED;
        short8 o;
#pragma unroll
        for (int i = 0; i < 8; ++i) o[i] = (short)f2bf((v[i]-mu)*rstd*g[t*8+i] + be[t*8+i]);
        *(short8*)(y + t*8) = o;
    }
}

// ---------------------------------------------------------------------------
// fp32 W[K][N] -> bf16 Wt[N][K] (transpose + convert), 32x32 LDS tiles
// ---------------------------------------------------------------------------
__global__ __launch_bounds__(256)
void cvt_transpose(const float* __restrict__ W, unsigned short* __restrict__ Wt, int K, int N)
{
    __shared__ unsigned short T[32][33];
    const int t = threadIdx.x;
    const long n0 = (long)blockIdx.x*32, k0 = (long)blockIdx.y*32;
    {
        const int r = t >> 3, c = (t & 7)*4;
        const float4 vv = *(const float4*)&W[(k0 + r)*N + n0 + c];
        T[r][c+0] = f2bf(vv.x); T[r][c+1] = f2bf(vv.y);
        T[r][c+2] = f2bf(vv.z); T[r][c+3] = f2bf(vv.w);
    }
    __syncthreads();
    const int rn = t >> 3, kk = (t & 7)*4;
    unsigned int p0 = (unsigned int)T[kk+0][rn] | ((unsigned int)T[kk+1][rn] << 16);
    unsigned int p1 = (unsigned int)T[kk+2][rn] | ((unsigned int)T[kk+3][rn] << 16);
    unsigned int* dst = (unsigned int*)&Wt[(n0 + rn)*K + k0 + kk];
    dst[0] = p0; dst[1] = p1;
}

__global__ __launch_bounds__(256)
void cvt_f32_bf16(const float* __restrict__ X, unsigned short* __restrict__ Y, long n)
{
    const long i = ((long)blockIdx.x*256 + threadIdx.x)*8;
    if (i >= n) return;
    const float4 a = *(const float4*)&X[i];
    const float4 b = *(const float4*)&X[i+4];
    short8 o;
    o[0]=(short)f2bf(a.x); o[1]=(short)f2bf(a.y); o[2]=(short)f2bf(a.z); o[3]=(short)f2bf(a.w);
    o[4]=(short)f2bf(b.x); o[5]=(short)f2bf(b.y); o[6]=(short)f2bf(b.z); o[7]=(short)f2bf(b.w);
    *(short8*)&Y[i] = o;
}

__global__ __launch_bounds__(256)
void concat_bias(const float* __restrict__ bq, const float* __restrict__ bk,
                 const float* __restrict__ bv, float* __restrict__ out)
{
    const int i = blockIdx.x*256 + threadIdx.x;
    if (i < 2048) out[i] = bq[i];
    else if (i < 4096) out[i] = bk[i-2048];
    else if (i < 6144) out[i] = bv[i-4096];
}

// ---------------------------------------------------------------------------
extern "C" void kernel_launch(void* const* d_in, const int* in_sizes, int n_in,
                              void* d_out, int out_size, void* d_ws, size_t ws_size,
                              hipStream_t stream)
{
    const float* x   = (const float*)d_in[0];
    const float* Wq  = (const float*)d_in[1];
    const float* bq  = (const float*)d_in[2];
    const float* Wk  = (const float*)d_in[3];
    const float* bk  = (const float*)d_in[4];
    const float* Wv  = (const float*)d_in[5];
    const float* bv  = (const float*)d_in[6];
    const float* Wo  = (const float*)d_in[7];
    const float* bo  = (const float*)d_in[8];
    const float* g1  = (const float*)d_in[9];
    const float* b1  = (const float*)d_in[10];
    const float* g2v = (const float*)d_in[11];
    const float* b2v = (const float*)d_in[12];
    const float* W1  = (const float*)d_in[13];
    const float* bf1 = (const float*)d_in[14];
    const float* W2  = (const float*)d_in[15];
    const float* bf2 = (const float*)d_in[16];
    float* out = (float*)d_out;

    // ---- workspace arena (byte offsets; total 184,573,952 B < 192 MiB) ----
    char* ws = (char*)d_ws;
    unsigned short* Wqkvt = (unsigned short*)(ws + 0);          // 25.2 MB [dead after GEMM1]
    unsigned short* Wot   = (unsigned short*)(ws + 25165824);   //  8.4 MB
    unsigned short* W1t   = (unsigned short*)(ws + 33554432);   // 33.6 MB
    unsigned short* W2t   = (unsigned short*)(ws + 67108864);   // 33.6 MB
    float*          bqkv  = (float*)         (ws + 100663296);  // 24 KB
    char* arenaA = ws + 100687872;                              // 67.1 MB arena
    unsigned short* xb   = (unsigned short*)(arenaA);           // 16.8 MB [cvt_x, GEMM1]
    unsigned short* qkv  = (unsigned short*)(arenaA + 16777216);// 50.3 MB [GEMM1, GEMM2]
    unsigned short* res1 = (unsigned short*)(arenaA);           // reuse xb slot [GEMM2, LN1]
    unsigned short* ff   = (unsigned short*)(arenaA);           // full arena [GEMM3, GEMM4]
    unsigned short* hb   = (unsigned short*)(ws + 167796736);   // 16.8 MB [LN1, GEMM4]
    unsigned short* res2 = (unsigned short*)(ws + 0);           // reuse Wqkvt slot [GEMM4, LN2]

    const dim3 blk(256);
    const dim3 blk8(512);

    // weights: fp32 -> bf16 transposed
    cvt_transpose<<<dim3(64,64),  blk, 0, stream>>>(Wq, Wqkvt,             2048, 2048);
    cvt_transpose<<<dim3(64,64),  blk, 0, stream>>>(Wk, Wqkvt + 2048*2048, 2048, 2048);
    cvt_transpose<<<dim3(64,64),  blk, 0, stream>>>(Wv, Wqkvt + 2*2048*2048, 2048, 2048);
    cvt_transpose<<<dim3(64,64),  blk, 0, stream>>>(Wo, Wot, 2048, 2048);
    cvt_transpose<<<dim3(256,64), blk, 0, stream>>>(W1, W1t, 2048, 8192);
    cvt_transpose<<<dim3(64,256), blk, 0, stream>>>(W2, W2t, 8192, 2048);
    concat_bias<<<dim3(24), blk, 0, stream>>>(bq, bk, bv, bqkv);
    cvt_f32_bf16<<<dim3(4096), blk, 0, stream>>>(x, xb, (long)TOK*EMBED);

    // fused QKV projection -> qkv[4096][6144]  (128x256 tiles, 768 blocks = 3 waves)
    gemm8p<128,0><<<dim3(24,32), blk8, 0, stream>>>(xb, Wqkvt, bqkv, nullptr, qkv, TOK, 6144, 2048, 2048);
    // flash attention (O overwrites q-columns in-place); 512 blocks (QBLK=128)
    attn_flash<<<dim3(512), blk, 0, stream>>>(qkv);
    // output projection + residual(x, fp32) — stays on 128x128 kernel (grid shape)
    gemm_bf16<1><<<dim3(16,32), blk, 0, stream>>>(qkv, Wot, bo, x, res1, TOK, 2048, 2048, 6144);
    ln_bf16<0><<<dim3(4096), blk, 0, stream>>>(res1, g1, b1, hb);
    // FFN1 + GELU (256x256 tiles, 512 blocks = 2 waves)
    gemm8p<256,2><<<dim3(32,16), blk8, 0, stream>>>(hb, W1t, bf1, nullptr, ff, TOK, 8192, 2048, 2048);
    // FFN2 + resid bf16 (128x256 tiles, 256 blocks = 1 wave; K=8192)
    gemm8p<128,3><<<dim3(8,32), blk8, 0, stream>>>(ff, W2t, bf2, hb, res2, TOK, 2048, 8192, 8192);
    ln_bf16<1><<<dim3(4096), blk, 0, stream>>>(res2, g2v, b2v, out);
}

// Round 8
// 912.243 us; speedup vs baseline: 1.1131x; 1.0005x over previous
//
#include <hip/hip_runtime.h>
#include <math.h>

#define EMBED 2048
#define DFF   8192
#define TOK   4096
#define SEQ   2048
#define HEADS 16
#define HD    128
#define LDQ   6144   // qkv row stride in elements (q|k|v concatenated)

typedef __attribute__((ext_vector_type(8))) short short8;
typedef __attribute__((ext_vector_type(4))) float f32x4;

__device__ __forceinline__ unsigned short f2bf(float f) {
    unsigned int u = __float_as_uint(f);
    return (unsigned short)((u + 0x7FFFu + ((u >> 16) & 1u)) >> 16);  // RNE
}
__device__ __forceinline__ float bf2f(unsigned short s) {
    return __uint_as_float(((unsigned int)s) << 16);
}
// 2^x via v_exp_f32 (native base-2). NOTE: name must not be __exp2f — glibc
// math.h declares that symbol and the collision breaks gfx950 compilation.
__device__ __forceinline__ float exp2_fast(float x) {
    return __builtin_amdgcn_exp2f(x);
}

// async global->LDS, 16B per lane. LDS dest = wave-uniform base + lane*16.
__device__ __forceinline__ void async16(const void* g, void* l) {
    __builtin_amdgcn_global_load_lds((const __attribute__((address_space(1))) void*)g,
                                     (__attribute__((address_space(3))) void*)l, 16, 0, 0);
}

// fast GELU (tanh form): v * sigmoid(1.5957691*(v + 0.044715 v^3)); |err|<~1e-3
__device__ __forceinline__ float gelu_fast(float v) {
    const float y = 1.5957691216057308f * (v + 0.044715f * v * v * v);
    return v / (1.0f + __expf(-y));
}

// ---------------------------------------------------------------------------
// R12: 8-wave counted-vmcnt GEMM (T3+T4+T2+T5) + T1 XCD-chunked swizzle.
// C[M,N](bf16) = A[M,K](bf16) @ Wt[N,K](bf16)^T + bias (+epilogue).
// 512 thr = 8 waves (2M x 4N). Tile BM x 256, BK=64 as two 32-K slices.
// Pipeline: stage order per K-tile is [slice0][slice1], each LA+2
// loads/thread. Phase kk waits vmcnt(LA+2) (newest slice-set may fly),
// raw s_barrier, issues next tile's slice kk, ds_reads (both-sides XOR
// swizzle, conflict-free), setprio-wrapped MFMAs. Never vmcnt(0) in-loop.
// T1 swizzle (R9 evidence: old FFN1 fetched 134 MB vs ~50 MB unique —
// per-XCD L2 thrash): lin = (orig&7)*(nwg/8)+orig/8, decoded M-fastest so
// each XCD owns contiguous N-panels; resident B working set 1-2 MB < 4 MiB
// L2; A streams via L3. Requires nwg%8==0 (all grids: 768/512/256/256).
// MODE: 0 plain, 1 +resid f32, 2 +GELU, 3 +resid bf16. Output bf16.
// ---------------------------------------------------------------------------
template<int BM, int MODE>
__global__ __launch_bounds__(512, 2)
void gemm8p(const unsigned short* __restrict__ A, const unsigned short* __restrict__ B,
            const float* __restrict__ bias, const void* __restrict__ resid,
            unsigned short* __restrict__ C, int M, int N, int K, int lda)
{
    constexpr int ASLICE = BM * 32;       // shorts per A K-slice
    constexpr int BSLICE = 256 * 32;      // shorts per B K-slice
    constexpr int LA = BM / 128;          // A loads/thread/slice (2 or 1)
    constexpr int MF = BM / 32;           // m-frags per wave (8 or 4)
    __shared__ __align__(16) unsigned short sm[4*ASLICE + 4*BSLICE];

    const int t = threadIdx.x;
    const int w = t >> 6, l = t & 63;
    const int quad = l >> 4, m16 = l & 15;
    const int wm = w >> 2, wn = w & 3;

    // T1: XCD-chunked bijective remap (HW: XCD = dispatch%8). M-fastest decode.
    const int nwg = gridDim.x * gridDim.y;
    const int orig = blockIdx.y * gridDim.x + blockIdx.x;
    const int lin = (orig & 7) * (nwg >> 3) + (orig >> 3);
    const int myt = lin % gridDim.y;      // M-tile (fastest within XCD chunk)
    const int nxt = lin / gridDim.y;      // N-tile
    const long bm = (long)myt * BM, bn = (long)nxt * 256;

    f32x4 acc[MF][4] = {};

    const unsigned short* Ag = A + (size_t)bm*lda;
    const unsigned short* Bg = B + (size_t)bn*K;

    // staging lambdas: element e = p*512 + t ; r = e>>2 ; s = e&3
    auto stageA = [&](int buf, int ks, int k0) {
#pragma unroll
        for (int p = 0; p < LA; ++p) {
            const int e = p*512 + t;
            const int r = e >> 2, s = e & 3;
            const int gc = k0 + ks*32 + (s ^ ((r >> 1) & 3))*8;
            async16(Ag + (size_t)r*lda + gc,
                    sm + buf*2*ASLICE + ks*ASLICE + (p*512 + w*64)*8);
        }
    };
    auto stageB = [&](int buf, int ks, int k0) {
#pragma unroll
        for (int p = 0; p < 2; ++p) {
            const int e = p*512 + t;
            const int r = e >> 2, s = e & 3;
            const int gc = k0 + ks*32 + (s ^ ((r >> 1) & 3))*8;
            async16(Bg + (size_t)r*K + gc,
                    sm + 4*ASLICE + buf*2*BSLICE + ks*BSLICE + (p*512 + w*64)*8);
        }
    };

    // prologue: tile 0, both slices
    stageA(0, 0, 0); stageB(0, 0, 0);
    stageA(0, 1, 0); stageB(0, 1, 0);

    const int iters = K >> 6;
    for (int it = 0; it < iters; ++it) {
        const int cur = it & 1;
        const bool pre = (it + 1 < iters);
        const int kn = (it + 1) << 6;

#pragma unroll
        for (int kk = 0; kk < 2; ++kk) {
            // wait: everything older than the newest slice-set has landed
            if (kk == 0 || pre) {
                if constexpr (BM == 256) asm volatile("s_waitcnt vmcnt(4)" ::: "memory");
                else                     asm volatile("s_waitcnt vmcnt(3)" ::: "memory");
            } else {
                asm volatile("s_waitcnt vmcnt(0)" ::: "memory");
            }
            __builtin_amdgcn_s_barrier();
            if (pre) { stageA(cur ^ 1, kk, kn); stageB(cur ^ 1, kk, kn); }

            const unsigned short* Ab = sm + cur*2*ASLICE + kk*ASLICE;
            const unsigned short* Bb = sm + 4*ASLICE + cur*2*BSLICE + kk*BSLICE;
            short8 afr[MF], bfr[4];
#pragma unroll
            for (int m = 0; m < MF; ++m) {
                const int R = wm*(BM/2) + m*16 + m16;
                const int sl = quad ^ ((R >> 1) & 3);
                afr[m] = *(const short8*)(Ab + R*32 + sl*8);
            }
#pragma unroll
            for (int n = 0; n < 4; ++n) {
                const int R = wn*64 + n*16 + m16;
                const int sl = quad ^ ((R >> 1) & 3);
                bfr[n] = *(const short8*)(Bb + R*32 + sl*8);
            }
            __builtin_amdgcn_s_setprio(1);
#pragma unroll
            for (int m = 0; m < MF; ++m)
#pragma unroll
                for (int n = 0; n < 4; ++n)
                    acc[m][n] = __builtin_amdgcn_mfma_f32_16x16x32_bf16(afr[m], bfr[n], acc[m][n], 0, 0, 0);
            __builtin_amdgcn_s_setprio(0);
        }
    }

    // ---- epilogue: acc -> LDS (f32) -> coalesced bf16 stores, 64-row passes ----
    __syncthreads();               // full drain; K-loop LDS dead
    asm volatile("" ::: "memory");
    float* Cs = (float*)sm;        // Cs[64][260] f32 = 66,560 B (fits both BM)
    const int ecol = (t & 31) * 8;
    float bias8[8];
#pragma unroll
    for (int i = 0; i < 8; ++i) bias8[i] = bias[bn + ecol + i];

    constexpr int NP = BM / 64;
#pragma unroll
    for (int p = 0; p < NP; ++p) {
        if (p) __syncthreads();
        constexpr int HW = (NP == 4) ? 2 : 1;   // passes per wm
        const int pwm = p / HW;
        const int mp = (NP == 4) ? (p & 1)*4 : 0;
        if (wm == pwm) {
#pragma unroll
            for (int mi = 0; mi < 4; ++mi)
#pragma unroll
                for (int n = 0; n < 4; ++n)
#pragma unroll
                    for (int r = 0; r < 4; ++r)
                        Cs[(mi*16 + quad*4 + r)*260 + wn*64 + n*16 + m16] = acc[mp + mi][n][r];
        }
        __syncthreads();
#pragma unroll
        for (int j = 0; j < 4; ++j) {
            const int row = j*16 + (t >> 5);
            float v[8];
            *(f32x4*)&v[0] = *(const f32x4*)&Cs[row*260 + ecol];
            *(f32x4*)&v[4] = *(const f32x4*)&Cs[row*260 + ecol + 4];
            const long gr = bm + p*64 + row;
            const long go = gr*N + bn + ecol;
            float r8[8];
            if (MODE == 1) {
                *(f32x4*)&r8[0] = *(const f32x4*)((const float*)resid + go);
                *(f32x4*)&r8[4] = *(const f32x4*)((const float*)resid + go + 4);
            }
            short8 rb16;
            if (MODE == 3) rb16 = *(const short8*)((const unsigned short*)resid + go);
            short8 o;
#pragma unroll
            for (int i = 0; i < 8; ++i) {
                float y = v[i] + bias8[i];
                if (MODE == 1) y += r8[i];
                if (MODE == 3) y += bf2f((unsigned short)rb16[i]);
                if (MODE == 2) y = gelu_fast(y);
                o[i] = (short)f2bf(y);
            }
            *(short8*)&C[go] = o;
        }
    }
}

// ---------------------------------------------------------------------------
// Flash attention, bf16 MFMA. One block = (b, h, 128-row Q tile). 256 thr.
// (R9 structure: QBLK=128 dual-accumulate, XCD-chunked swizzle, single
// barrier/iter, base-2 softmax, exact rescale-skip. Unchanged — measured
// 172.8 us, the top dispatch; 32x32-MFMA rewrite is the next-round lever.)
// ---------------------------------------------------------------------------
__global__ __launch_bounds__(256, 2)
void attn_flash(unsigned short* __restrict__ qkv)
{
    __shared__ unsigned short Ks2[2][64*128]; // K dbuf (32,768 B)
    __shared__ unsigned short Vt2[2][128*72]; // V^T dbuf [d][j] (36,864 B); Q-staging overlay
    __shared__ unsigned short Ps[4*16*72];    // per-wave P scratch (9,216 B)

    const int t = threadIdx.x;
    const int w = t >> 6, l = t & 63;
    const int quad = l >> 4, m16 = l & 15;

    // XCD-chunked decode: 512 dispatches, XCD = d&7, 64 blocks/XCD = 4 bh's
    const int dd = blockIdx.x;
    const int bh = (dd & 7)*4 + ((dd >> 3) >> 4);  // 0..31
    const int qt = (dd >> 3) & 15;                 // 0..15 (128-row tiles)
    const int b = bh >> 4, h = bh & 15;

    const long rowq = (long)b*SEQ + qt*128;
    const long rowb = (long)b*SEQ;
    const int qc = h*HD;
    const int kc = EMBED + h*HD;
    const int vc = 2*EMBED + h*HD;

    const int rbase = w*4 + (l >> 4);   // K/Q staging row base
    const int slot  = l & 15;           // K/Q staging 16B slot
    const int vslot = t & 15;           // V staging d-slot
    const int vrp   = t >> 4;           // V staging row-pair base

    unsigned short* QsOv = (unsigned short*)Vt2;   // Q overlay: 128*128*2 = 32 KB <= 36,864 B

    // ---- prologue: V0 -> regs (oldest vmcnt entries), Q -> QsOv, K0 -> Ks2[0] ----
    short8 va[2], vb[2];
#pragma unroll
    for (int u = 0; u < 2; ++u) {
        const int rp = u*16 + vrp;
        va[u] = *(const short8*)(qkv + (rowb + 2*rp    )*LDQ + vc + vslot*8);
        vb[u] = *(const short8*)(qkv + (rowb + 2*rp + 1)*LDQ + vc + vslot*8);
    }
#pragma unroll
    for (int u = 0; u < 8; ++u) {   // Q: 128 rows
        const int row = u*16 + rbase;
        const int c = slot ^ ((row >> 1) & 7);
        async16(qkv + (rowq + row)*LDQ + qc + c*8, QsOv + u*2048 + w*512);
    }
#pragma unroll
    for (int u = 0; u < 4; ++u) {   // K0: 64 rows
        const int row = u*16 + rbase;
        const int c = slot ^ ((row >> 1) & 7);
        async16(qkv + (rowb + row)*LDQ + kc + c*8, &Ks2[0][u*2048 + w*512]);
    }
    __syncthreads();   // Q + K0 staged

    // Q A-frags: wave w owns q-rows [w*32, w*32+32), two 16-row halves
    short8 af[2][4];
#pragma unroll
    for (int qh = 0; qh < 2; ++qh)
#pragma unroll
        for (int ks = 0; ks < 4; ++ks) {
            const int row = w*32 + qh*16 + m16;
            const int sl = (4*ks + quad) ^ ((row >> 1) & 7);
            af[qh][ks] = *(const short8*)&QsOv[row*128 + sl*8];
        }
    __syncthreads();   // all waves done reading Q; Vt2 free

    // pack V0 -> Vt2[0]
#pragma unroll
    for (int u = 0; u < 2; ++u) {
        const int rp = u*16 + vrp;
#pragma unroll
        for (int i = 0; i < 8; ++i) {
            const int dv = vslot*8 + i;
            const int col = (2*rp) ^ (((dv >> 5) & 3) << 3);
            unsigned int pv = (unsigned int)(unsigned short)va[u][i] |
                              ((unsigned int)(unsigned short)vb[u][i] << 16);
            *(unsigned int*)&Vt2[0][dv*72 + col] = pv;
        }
    }
    __syncthreads();   // Vt2[0] visible; ready for iter 0

    f32x4 O[2][8] = {};
    float mrun[2][4], lrun[2][4];
#pragma unroll
    for (int qh = 0; qh < 2; ++qh)
#pragma unroll
        for (int r = 0; r < 4; ++r) { mrun[qh][r] = -1e30f; lrun[qh][r] = 0.f; }
    unsigned short* Pw = Ps + w*16*72;
    const float SC = 0.08838834764831845f * 1.4426950408889634f; // 1/sqrt(128) * log2(e)

    for (int kt = 0; kt < SEQ/64; ++kt) {
        const int cur = kt & 1;
        const bool pre = (kt + 1 < SEQ/64);
        const long rowkv = rowb + (long)(kt + 1)*64;

        // ---- issue next tile's loads: V -> regs, K -> Ks2[cur^1] async ----
        if (pre) {
#pragma unroll
            for (int u = 0; u < 2; ++u) {
                const int rp = u*16 + vrp;
                va[u] = *(const short8*)(qkv + (rowkv + 2*rp    )*LDQ + vc + vslot*8);
                vb[u] = *(const short8*)(qkv + (rowkv + 2*rp + 1)*LDQ + vc + vslot*8);
            }
#pragma unroll
            for (int u = 0; u < 4; ++u) {
                const int row = u*16 + rbase;
                const int c = slot ^ ((row >> 1) & 7);
                async16(qkv + (rowkv + row)*LDQ + kc + c*8, &Ks2[cur^1][u*2048 + w*512]);
            }
        }

        // ---- S = Q K^T, both q-halves share each K-fragment read ----
        f32x4 S[2][4];
#pragma unroll
        for (int ns = 0; ns < 4; ++ns) {
            f32x4 a0 = {0.f,0.f,0.f,0.f}, a1 = {0.f,0.f,0.f,0.f};
            const int row = ns*16 + m16;
            const int swr = (row >> 1) & 7;
#pragma unroll
            for (int ks = 0; ks < 4; ++ks) {
                const int sl = (4*ks + quad) ^ swr;
                const short8 bfr = *(const short8*)&Ks2[cur][row*128 + sl*8];
                a0 = __builtin_amdgcn_mfma_f32_16x16x32_bf16(af[0][ks], bfr, a0, 0, 0, 0);
                a1 = __builtin_amdgcn_mfma_f32_16x16x32_bf16(af[1][ks], bfr, a1, 0, 0, 0);
            }
#pragma unroll
            for (int r = 0; r < 4; ++r) { a0[r] *= SC; a1[r] *= SC; }
            S[0][ns] = a0; S[1][ns] = a1;
        }

        // ---- per-half: online softmax -> P -> PV (Pw reused; same-wave order) ----
#pragma unroll
        for (int qh = 0; qh < 2; ++qh) {
            float al[4], rs4[4];
#pragma unroll
            for (int r = 0; r < 4; ++r) {
                float tm = fmaxf(fmaxf(S[qh][0][r], S[qh][1][r]), fmaxf(S[qh][2][r], S[qh][3][r]));
                tm = fmaxf(tm, __shfl_xor(tm, 1));
                tm = fmaxf(tm, __shfl_xor(tm, 2));
                tm = fmaxf(tm, __shfl_xor(tm, 4));
                tm = fmaxf(tm, __shfl_xor(tm, 8));
                const float mn = fmaxf(mrun[qh][r], tm);
                al[r] = exp2_fast(mrun[qh][r] - mn);
                mrun[qh][r] = mn;
                rs4[r] = 0.f;
            }
#pragma unroll
            for (int ns = 0; ns < 4; ++ns)
#pragma unroll
                for (int r = 0; r < 4; ++r) {
                    const float p = exp2_fast(S[qh][ns][r] - mrun[qh][r]);
                    rs4[r] += p;
                    Pw[(quad*4 + r)*72 + ns*16 + m16] = f2bf(p);
                }
#pragma unroll
            for (int r = 0; r < 4; ++r) {
                rs4[r] += __shfl_xor(rs4[r], 1);
                rs4[r] += __shfl_xor(rs4[r], 2);
                rs4[r] += __shfl_xor(rs4[r], 4);
                rs4[r] += __shfl_xor(rs4[r], 8);
                lrun[qh][r] = lrun[qh][r]*al[r] + rs4[r];
            }
            // al==1.0 exactly when the running max didn't grow -> skip is exact
            if (__any((al[0] != 1.f) | (al[1] != 1.f) | (al[2] != 1.f) | (al[3] != 1.f))) {
#pragma unroll
                for (int i = 0; i < 8; ++i)
#pragma unroll
                    for (int r = 0; r < 4; ++r) O[qh][i][r] *= al[r];
            }

            // pack next V tile late (after most compute, before final PV)
            if (qh == 1 && pre) {
#pragma unroll
                for (int u = 0; u < 2; ++u) {
                    const int rp = u*16 + vrp;
#pragma unroll
                    for (int i = 0; i < 8; ++i) {
                        const int dv = vslot*8 + i;
                        const int col = (2*rp) ^ (((dv >> 5) & 3) << 3);
                        unsigned int pv = (unsigned int)(unsigned short)va[u][i] |
                                          ((unsigned int)(unsigned short)vb[u][i] << 16);
                        *(unsigned int*)&Vt2[cur^1][dv*72 + col] = pv;
                    }
                }
            }

            // O[qh] += P V
#pragma unroll
            for (int ks2 = 0; ks2 < 2; ++ks2) {
                const short8 ap = *(const short8*)&Pw[m16*72 + ks2*32 + quad*8];
#pragma unroll
                for (int ds = 0; ds < 8; ++ds) {
                    const int dv = ds*16 + m16;
                    const int jcol = (ks2*32 + quad*8) ^ (((dv >> 5) & 3) << 3);
                    const short8 bv = *(const short8*)&Vt2[cur][dv*72 + jcol];
                    O[qh][ds] = __builtin_amdgcn_mfma_f32_16x16x32_bf16(ap, bv, O[qh][ds], 0, 0, 0);
                }
            }
        }

        // single barrier: drains K glds (Ks2[cur^1] ready), publishes Vt2[cur^1],
        // fences all reads of Ks2[cur]/Vt2[cur] before iter kt+1 overwrites them.
        __syncthreads();
    }

    // ---- normalize + write O over the Q columns ----
    float inv[2][4];
#pragma unroll
    for (int qh = 0; qh < 2; ++qh)
#pragma unroll
        for (int r = 0; r < 4; ++r) inv[qh][r] = 1.0f / lrun[qh][r];
#pragma unroll
    for (int qh = 0; qh < 2; ++qh)
#pragma unroll
        for (int ds = 0; ds < 8; ++ds)
#pragma unroll
            for (int r = 0; r < 4; ++r) {
                const long row = rowq + w*32 + qh*16 + quad*4 + r;
                qkv[row*LDQ + qc + ds*16 + m16] = f2bf(O[qh][ds][r] * inv[qh][r]);
            }
}

// ---------------------------------------------------------------------------
// LayerNorm over bf16 rows. OUTF32=1 writes fp32 (final output), else bf16.
// ---------------------------------------------------------------------------
template<int OUTF32>
__global__ __launch_bounds__(256)
void ln_bf16(const unsigned short* __restrict__ X, const float* __restrict__ g,
             const float* __restrict__ be, void* __restrict__ Y)
{
    __shared__ float r1[256], r2[256];
    const int t = threadIdx.x;
    const long row = blockIdx.x;
    const unsigned short* x = X + row*EMBED;
    float v[8];
    const short8 xv = *(const short8*)(x + t*8);
    float s = 0.f, s2 = 0.f;
#pragma unroll
    for (int i = 0; i < 8; ++i) {
        v[i] = bf2f((unsigned short)xv[i]);
        s += v[i]; s2 += v[i]*v[i];
    }
    r1[t] = s; r2[t] = s2;
    __syncthreads();
    for (int k = 128; k > 0; k >>= 1) {
        if (t < k) { r1[t] += r1[t+k]; r2[t] += r2[t+k]; }
        __syncthreads();
    }
    const float mu = r1[0] * (1.0f/EMBED);
    const float var = r2[0] * (1.0f/EMBED) - mu*mu;
    const float rstd = rsqrtf(var + 1e-5f);
    if (OUTF32) {
        float* y = (float*)Y + row*EMBED + t*8;
#pragma unroll
        for (int i = 0; i < 8; ++i) y[i] = (v[i]-mu)*rstd*g[t*8+i] + be[t*8+i];
    } else {
        unsigned short* y = (unsigned short*)Y + row*EMBED;
        short8 o;
#pragma unroll
        for (int i = 0; i < 8; ++i) o[i] = (short)f2bf((v[i]-mu)*rstd*g[t*8+i] + be[t*8+i]);
        *(short8*)(y + t*8) = o;
    }
}

// ---------------------------------------------------------------------------
// fp32 W[K][N] -> bf16 Wt[N][K] (transpose + convert), 32x32 LDS tiles
// ---------------------------------------------------------------------------
__global__ __launch_bounds__(256)
void cvt_transpose(const float* __restrict__ W, unsigned short* __restrict__ Wt, int K, int N)
{
    __shared__ unsigned short T[32][33];
    const int t = threadIdx.x;
    const long n0 = (long)blockIdx.x*32, k0 = (long)blockIdx.y*32;
    {
        const int r = t >> 3, c = (t & 7)*4;
        const float4 vv = *(const float4*)&W[(k0 + r)*N + n0 + c];
        T[r][c+0] = f2bf(vv.x); T[r][c+1] = f2bf(vv.y);
        T[r][c+2] = f2bf(vv.z); T[r][c+3] = f2bf(vv.w);
    }
    __syncthreads();
    const int rn = t >> 3, kk = (t & 7)*4;
    unsigned int p0 = (unsigned int)T[kk+0][rn] | ((unsigned int)T[kk+1][rn] << 16);
    unsigned int p1 = (unsigned int)T[kk+2][rn] | ((unsigned int)T[kk+3][rn] << 16);
    unsigned int* dst = (unsigned int*)&Wt[(n0 + rn)*K + k0 + kk];
    dst[0] = p0; dst[1] = p1;
}

__global__ __launch_bounds__(256)
void cvt_f32_bf16(const float* __restrict__ X, unsigned short* __restrict__ Y, long n)
{
    const long i = ((long)blockIdx.x*256 + threadIdx.x)*8;
    if (i >= n) return;
    const float4 a = *(const float4*)&X[i];
    const float4 b = *(const float4*)&X[i+4];
    short8 o;
    o[0]=(short)f2bf(a.x); o[1]=(short)f2bf(a.y); o[2]=(short)f2bf(a.z); o[3]=(short)f2bf(a.w);
    o[4]=(short)f2bf(b.x); o[5]=(short)f2bf(b.y); o[6]=(short)f2bf(b.z); o[7]=(short)f2bf(b.w);
    *(short8*)&Y[i] = o;
}

__global__ __launch_bounds__(256)
void concat_bias(const float* __restrict__ bq, const float* __restrict__ bk,
                 const float* __restrict__ bv, float* __restrict__ out)
{
    const int i = blockIdx.x*256 + threadIdx.x;
    if (i < 2048) out[i] = bq[i];
    else if (i < 4096) out[i] = bk[i-2048];
    else if (i < 6144) out[i] = bv[i-4096];
}

// ---------------------------------------------------------------------------
extern "C" void kernel_launch(void* const* d_in, const int* in_sizes, int n_in,
                              void* d_out, int out_size, void* d_ws, size_t ws_size,
                              hipStream_t stream)
{
    const float* x   = (const float*)d_in[0];
    const float* Wq  = (const float*)d_in[1];
    const float* bq  = (const float*)d_in[2];
    const float* Wk  = (const float*)d_in[3];
    const float* bk  = (const float*)d_in[4];
    const float* Wv  = (const float*)d_in[5];
    const float* bv  = (const float*)d_in[6];
    const float* Wo  = (const float*)d_in[7];
    const float* bo  = (const float*)d_in[8];
    const float* g1  = (const float*)d_in[9];
    const float* b1  = (const float*)d_in[10];
    const float* g2v = (const float*)d_in[11];
    const float* b2v = (const float*)d_in[12];
    const float* W1  = (const float*)d_in[13];
    const float* bf1 = (const float*)d_in[14];
    const float* W2  = (const float*)d_in[15];
    const float* bf2 = (const float*)d_in[16];
    float* out = (float*)d_out;

    // ---- workspace arena (byte offsets; total 184,573,952 B < 192 MiB) ----
    char* ws = (char*)d_ws;
    unsigned short* Wqkvt = (unsigned short*)(ws + 0);          // 25.2 MB [dead after GEMM1]
    unsigned short* Wot   = (unsigned short*)(ws + 25165824);   //  8.4 MB
    unsigned short* W1t   = (unsigned short*)(ws + 33554432);   // 33.6 MB
    unsigned short* W2t   = (unsigned short*)(ws + 67108864);   // 33.6 MB
    float*          bqkv  = (float*)         (ws + 100663296);  // 24 KB
    char* arenaA = ws + 100687872;                              // 67.1 MB arena
    unsigned short* xb   = (unsigned short*)(arenaA);           // 16.8 MB [cvt_x, GEMM1]
    unsigned short* qkv  = (unsigned short*)(arenaA + 16777216);// 50.3 MB [GEMM1, GEMM2]
    unsigned short* res1 = (unsigned short*)(arenaA);           // reuse xb slot [GEMM2, LN1]
    unsigned short* ff   = (unsigned short*)(arenaA);           // full arena [GEMM3, GEMM4]
    unsigned short* hb   = (unsigned short*)(ws + 167796736);   // 16.8 MB [LN1, GEMM4]
    unsigned short* res2 = (unsigned short*)(ws + 0);           // reuse Wqkvt slot [GEMM4, LN2]

    const dim3 blk(256);
    const dim3 blk8(512);

    // weights: fp32 -> bf16 transposed
    cvt_transpose<<<dim3(64,64),  blk, 0, stream>>>(Wq, Wqkvt,             2048, 2048);
    cvt_transpose<<<dim3(64,64),  blk, 0, stream>>>(Wk, Wqkvt + 2048*2048, 2048, 2048);
    cvt_transpose<<<dim3(64,64),  blk, 0, stream>>>(Wv, Wqkvt + 2*2048*2048, 2048, 2048);
    cvt_transpose<<<dim3(64,64),  blk, 0, stream>>>(Wo, Wot, 2048, 2048);
    cvt_transpose<<<dim3(256,64), blk, 0, stream>>>(W1, W1t, 2048, 8192);
    cvt_transpose<<<dim3(64,256), blk, 0, stream>>>(W2, W2t, 8192, 2048);
    concat_bias<<<dim3(24), blk, 0, stream>>>(bq, bk, bv, bqkv);
    cvt_f32_bf16<<<dim3(4096), blk, 0, stream>>>(x, xb, (long)TOK*EMBED);

    // fused QKV projection -> qkv[4096][6144]  (128x256 tiles, 768 blocks)
    gemm8p<128,0><<<dim3(24,32), blk8, 0, stream>>>(xb, Wqkvt, bqkv, nullptr, qkv, TOK, 6144, 2048, 2048);
    // flash attention (O overwrites q-columns in-place); 512 blocks (QBLK=128)
    attn_flash<<<dim3(512), blk, 0, stream>>>(qkv);
    // output projection + residual(x, fp32)  (128x256 tiles, 256 blocks)
    gemm8p<128,1><<<dim3(8,32), blk8, 0, stream>>>(qkv, Wot, bo, x, res1, TOK, 2048, 2048, 6144);
    ln_bf16<0><<<dim3(4096), blk, 0, stream>>>(res1, g1, b1, hb);
    // FFN1 + GELU (256x256 tiles, 512 blocks)
    gemm8p<256,2><<<dim3(32,16), blk8, 0, stream>>>(hb, W1t, bf1, nullptr, ff, TOK, 8192, 2048, 2048);
    // FFN2 + resid bf16 (128x256 tiles, 256 blocks; K=8192)
    gemm8p<128,3><<<dim3(8,32), blk8, 0, stream>>>(ff, W2t, bf2, hb, res2, TOK, 2048, 8192, 8192);
    ln_bf16<1><<<dim3(4096), blk, 0, stream>>>(res2, g2v, b2v, out);
}